// Round 5
// baseline (5730.513 us; speedup 1.0000x reference)
//
#include <hip/hip_runtime.h>

// ---------------------------------------------------------------------------
// SimpleLSTM: 2-layer LSTM (B=32,T=512,D=512,H=1024) + output proj (O=512).
//   conv kernels : fp32 -> f16, weights rearranged into MFMA B-frag order
//   lstm_persist : 256 persistent WGs (1/CU), all 4 weight slices in LDS
//   wd_gemm      : Y = H1 @ Wd + bd
// R4: tree barrier, 1 barrier/step (22.7 -> 14.5 ms).
// R5: uncached h-exchange stores, direct-from-global A-frags (14.5 -> 8.3).
// R6: poll de-congestion + merged B(t)/A(t+1) phase (8.3 -> 7.6).
// R7: NO FENCES. h1a t-indexed; fresh-line reads need no invalidate (7.6->6.6).
// R8: h0a t-indexed too; all h reads plain cached loads (6.6 -> 5.8).
// R9: flat zero-RMW barrier — REGRESSED; reverted to R8 tree.
// R10: register-batched h loads (64 frags in flight) (5.4 -> 4.8 persist).
// R11: fused Wx0 GEMM, deleted zx0. FETCH/WRITE unchanged -> LLC-thrash
//     theory dead; ~350MB fetch is the intrinsic 8-XCD fan-out, ~267MB write
//     is 8B-store->32B-sector amplification. Kept the fusion (frees 128MiB
//     and a dispatch) but the in-loop placement regressed (4.8 -> 5.1).
// R12: SPLIT-PHASE BARRIER. The recurrence critical path is only the
//     A-chain (h0(t)->h0(t+1): 32 MFMAs); h1(t) has a full step of slack
//     before its first consumer. Two trees: tree A gates h0 reads, tree B
//     gates h1 reads one step behind. Per step: poll goA -> load H0 ->
//     32 MFMAs -> gates -> store h0 -> drain -> arrive A immediately; then
//     in the slack: poll goB(t-1) (already released), B-chain (64 MFMAs),
//     store h1, arrive B, precompute x(t+2)@Wx0. B-phase compute, drains
//     and skew leave the inter-step critical path.
// ---------------------------------------------------------------------------

typedef _Float16 half8  __attribute__((ext_vector_type(8)));
typedef float    floatx4 __attribute__((ext_vector_type(4)));

// ws layout (bytes)
#define WREC_OFF   0UL            // [256 wg][3 mat][128 kc][16 c][8] f16 = 24 MiB
#define WX0_OFF    25165824UL     // [256 wg][64 kc][16 c][8] f16        = 4 MiB
#define WD_OFF     29360128UL     // [32 nt][128 kc][16 c][8] f16        = 1 MiB
#define XH_OFF     30408704UL     // [512 t][32 b][512 d] f16            = 16 MiB
#define H1_OFF     47185920UL     // [512 t][32 m][1024 k] f16           = 32 MiB
#define H0_OFF     80740352UL     // [512 t][32 m][1024 k] f16           = 32 MiB
#define FLAGS_OFF  114294784UL    // 64 KiB: treeA @0, treeB @32KiB

__device__ __forceinline__ float fsig(float x){ return 1.0f/(1.0f + __expf(-x)); }
__device__ __forceinline__ float ftanhf(float x){
  float e = __expf(2.0f*fabsf(x));
  float r = 1.0f - 2.0f/(e + 1.0f);
  return copysignf(r, x);
}

// ---------------- weight conversion ----------------------------------------
__global__ void conv_wrec(const float* __restrict__ Wh0,
                          const float* __restrict__ Wx1,
                          const float* __restrict__ Wh1,
                          _Float16* __restrict__ out){
  int idx = blockIdx.x*256 + threadIdx.x;          // ((wg*3+mat)*128+kc)*16+c
  if (idx >= 256*3*128*16) return;
  int c  = idx & 15;
  int t1 = idx >> 4;
  int kc = t1 & 127;
  int t2 = t1 >> 7;
  int mat = t2 % 3;
  int wg  = t2 / 3;
  const float* W = (mat==0) ? Wh0 : (mat==1) ? Wx1 : Wh1;
  int col = (c>>2)*1024 + wg*4 + (c&3);
  _Float16* o = out + (size_t)idx*8;
  #pragma unroll
  for (int j=0;j<8;++j) o[j] = (_Float16)W[(kc*8+j)*4096 + col];
}

__global__ void conv_wx0(const float* __restrict__ W, _Float16* __restrict__ out){
  int idx = blockIdx.x*256 + threadIdx.x;          // ((wg*64+kc)*16+c)
  if (idx >= 256*64*16) return;
  int c  = idx & 15;
  int kc = (idx >> 4) & 63;
  int wg = idx >> 10;
  int col = (c>>2)*1024 + wg*4 + (c&3);
  _Float16* o = out + (size_t)idx*8;
  #pragma unroll
  for (int j=0;j<8;++j) o[j] = (_Float16)W[(kc*8+j)*4096 + col];
}

__global__ void conv_wd(const float* __restrict__ W, _Float16* __restrict__ out){
  int idx = blockIdx.x*256 + threadIdx.x;          // ((nt*128+kc)*16+c)
  if (idx >= 32*128*16) return;
  int c  = idx & 15;
  int kc = (idx >> 4) & 127;
  int nt = idx >> 11;
  int col = nt*16 + c;
  _Float16* o = out + (size_t)idx*8;
  #pragma unroll
  for (int j=0;j<8;++j) o[j] = (_Float16)W[(kc*8+j)*512 + col];
}

// x[b][t][d] fp32 -> xh[t*32+b][d] f16  (time-major rows)
__global__ void conv_x(const float* __restrict__ x, _Float16* __restrict__ xh){
  int idx = blockIdx.x*256 + threadIdx.x;          // [bt][dq], dq = d/4
  if (idx >= 2097152) return;
  int dq = idx & 127;
  int bt = idx >> 7;          // t*32 + b
  int b  = bt & 31;
  int t  = bt >> 5;
  float4 v = ((const float4*)x)[(size_t)(b*512 + t)*128 + dq];
  _Float16* o = xh + (size_t)idx*4;
  o[0]=(_Float16)v.x; o[1]=(_Float16)v.y; o[2]=(_Float16)v.z; o[3]=(_Float16)v.w;
}

// ---------------- persistent recurrent kernel ------------------------------
// LDS: w0 (Wh0), w1 (Wx1), w2 (Wh1) 32 KiB each + w3 (Wx0) 16 KiB = 112 KiB
#define AF(base, ks)  (*(const half8*)((base) + (ks)*32))
#define BF(w, ks)     (*(const half8*)((w) + (((ks)*4 + q)*16 + c)*8))

#define ARRIVE(gcnt, root, go, tgt)                                          \
  { unsigned o_ = __hip_atomic_fetch_add((gcnt), 1u, __ATOMIC_RELAXED,       \
                                         __HIP_MEMORY_SCOPE_AGENT);          \
    if (o_ == 8u*(tgt) - 1u){                                                \
      unsigned r_ = __hip_atomic_fetch_add((root), 1u, __ATOMIC_RELAXED,     \
                                           __HIP_MEMORY_SCOPE_AGENT);        \
      if (r_ == 32u*(tgt) - 1u){                                             \
        _Pragma("unroll")                                                    \
        for (int g2=0; g2<32; ++g2)                                          \
          __hip_atomic_store((go) + g2*64, (tgt), __ATOMIC_RELAXED,          \
                             __HIP_MEMORY_SCOPE_AGENT);                      \
      } } }

#define POLL(p, tgt)                                                         \
  while (__hip_atomic_load((p), __ATOMIC_RELAXED,                            \
                           __HIP_MEMORY_SCOPE_AGENT) < (tgt))                \
    __builtin_amdgcn_s_sleep(1);

// gate exchange + cell update + packed agent-scope store of h (cols wg*4..+3)
__device__ __forceinline__ void gates_store(floatx4 acc, float* cs,
    _Float16* dst, int g, int c, int mt, int q, int wg){
  #pragma unroll
  for (int r=0;r<4;++r){
    float v0 = acc[r];
    float v1 = __shfl_xor(v0, 4, 64);
    float v2 = __shfl_xor(v0, 8, 64);
    float v3 = __shfl_xor(v1, 8, 64);
    float zi = (g==0)?v0:(g==1)?v1:(g==2)?v2:v3;
    float zf = (g==0)?v1:(g==1)?v0:(g==2)?v3:v2;
    float zg = (g==0)?v2:(g==1)?v3:(g==2)?v0:v1;
    float zo = (g==0)?v3:(g==1)?v2:(g==2)?v1:v0;
    float cn = fsig(zf)*cs[r] + fsig(zi)*ftanhf(zg);
    cs[r] = cn;
    float hv = fsig(zo)*ftanhf(cn);
    unsigned hb16 = (unsigned)__builtin_bit_cast(unsigned short, (_Float16)hv);
    unsigned up   = (unsigned)__shfl_xor((int)hb16, 1, 64);
    if (g==0 && (c&1)==0)
      __hip_atomic_store((unsigned*)(dst + (mt*16 + q*4 + r)*1024 + wg*4 + c),
                         hb16 | (up<<16),
                         __ATOMIC_RELAXED, __HIP_MEMORY_SCOPE_AGENT);
  }
}

__global__ __launch_bounds__(128, 1) void lstm_persist(
    const _Float16* __restrict__ wrec, const _Float16* __restrict__ wx0a,
    const _Float16* __restrict__ xh,
    const float* __restrict__ b0g, const float* __restrict__ b1g,
    _Float16* __restrict__ h0a, _Float16* __restrict__ h1a,
    unsigned int* __restrict__ flags)
{
  extern __shared__ _Float16 lds[];
  _Float16* w0  = lds;            // 16384 halves (Wh0)
  _Float16* w1  = lds + 16384;    // (Wx1)
  _Float16* w2  = lds + 32768;    // (Wh1)
  _Float16* w3  = lds + 49152;    // 8192 halves (Wx0)

  const int wg = blockIdx.x, tid = threadIdx.x;
  const int wv = tid>>6, l = tid&63, q = l>>4, c = l&15;
  const int g = (c>>2);           // gate of own column
  const int mt = wv;              // wave0 rows 0-15, wave1 rows 16-31
  const int row = mt*16 + c;      // A-frag row this lane loads
  const int grp = wg >> 3;        // 32 groups of 8

  // tree A (h0): leaf lines @0, root @+8KiB, go lines @+16KiB
  unsigned int* gcntA = flags + grp*64;
  unsigned int* rootA = flags + 2048;
  unsigned int* goA   = flags + 4096;
  // tree B (h1): same shape at +32 KiB
  unsigned int* gcntB = flags + 8192 + grp*64;
  unsigned int* rootB = flags + 8192 + 2048;
  unsigned int* goB   = flags + 8192 + 4096;

  { // stage this WG's weight slices: 96 KiB wrec + 16 KiB wx0
    const uint4* srcA = (const uint4*)(wrec + (size_t)wg*49152);
    const uint4* srcB = (const uint4*)(wx0a + (size_t)wg*8192);
    uint4* dst = (uint4*)lds;
    for (int i=tid; i<6144; i+=128) dst[i] = srcA[i];
    for (int i=tid; i<1024; i+=128) dst[6144+i] = srcB[i];
  }
  float c0[4] = {0,0,0,0}, c1[4] = {0,0,0,0};
  const float b0v = b0g[g*1024 + wg*4 + (c&3)];
  const float b1v = b1g[g*1024 + wg*4 + (c&3)];
  __syncthreads();

  // ---------- prologue: h0(0) = act(x(0)@Wx0 + b0)  (h0(-1)=0) ----------
  {
    const _Float16* xb = xh + (size_t)row*512 + q*8;
    floatx4 p0={b0v,b0v,b0v,b0v}, p1={0,0,0,0};
    #pragma unroll
    for (int s=0; s<8; ++s){
      p0 = __builtin_amdgcn_mfma_f32_16x16x32_f16(AF(xb,s),   BF(w3,s),   p0,0,0,0);
      p1 = __builtin_amdgcn_mfma_f32_16x16x32_f16(AF(xb,8+s), BF(w3,8+s), p1,0,0,0);
    }
    floatx4 z = p0+p1;
    gates_store(z, c0, h0a, g, c, mt, q, wg);   // t = 0
  }
  __syncthreads();                               // drain h0(0) stores
  if (tid==0) ARRIVE(gcntA, rootA, goA, 1u);

  // Xacc for iteration 0: x(1)@Wx0 + b0
  floatx4 xA0, xA1;
  {
    const _Float16* xb = xh + (size_t)(32 + row)*512 + q*8;
    half8 X[16];
    #pragma unroll
    for (int s=0; s<16; ++s) X[s] = AF(xb, s);
    xA0=(floatx4){b0v,b0v,b0v,b0v}; xA1=(floatx4){0,0,0,0};
    #pragma unroll
    for (int s=0; s<8; ++s){
      xA0 = __builtin_amdgcn_mfma_f32_16x16x32_f16(X[s],   BF(w3,s),   xA0,0,0,0);
      xA1 = __builtin_amdgcn_mfma_f32_16x16x32_f16(X[8+s], BF(w3,8+s), xA1,0,0,0);
    }
  }

  for (int t=0; t<512; ++t){
    const unsigned tA = (unsigned)(t+1);

    // ---------- A-phase: the recurrence critical path ----------
    if (tid==0){ POLL(goA + grp*64, tA); }       // h0(t) published
    __syncthreads();

    const _Float16* h0c = h0a + (size_t)t*32768 + row*1024 + q*8;
    half8 H0[32];
    #pragma unroll
    for (int s=0; s<32; ++s) H0[s] = AF(h0c, s);

    if (t < 511){
      floatx4 aA0=xA0, aA1=xA1;
      #pragma unroll
      for (int s=0; s<16; ++s){
        aA0 = __builtin_amdgcn_mfma_f32_16x16x32_f16(H0[s],    BF(w0,s),    aA0,0,0,0);
        aA1 = __builtin_amdgcn_mfma_f32_16x16x32_f16(H0[16+s], BF(w0,16+s), aA1,0,0,0);
      }
      floatx4 z0 = aA0+aA1;
      gates_store(z0, c0, h0a + (size_t)(t+1)*32768, g, c, mt, q, wg);
      __syncthreads();                           // drain h0(t+1) stores
      if (tid==0) ARRIVE(gcntA, rootA, goA, tA+1);
    }

    // ---------- B-phase: one step of slack ----------
    floatx4 aC0={0,0,0,0}, aC1={0,0,0,0};
    if (t > 0){
      if (tid==0){ POLL(goB + grp*64, (unsigned)t); }   // h1(t-1) published
      __syncthreads();
      const _Float16* h1p = h1a + (size_t)(t-1)*32768 + row*1024 + q*8;
      half8 H1[32];
      #pragma unroll
      for (int s=0; s<32; ++s) H1[s] = AF(h1p, s);
      #pragma unroll
      for (int s=0; s<16; ++s){
        aC0 = __builtin_amdgcn_mfma_f32_16x16x32_f16(H1[s],    BF(w2,s),    aC0,0,0,0);
        aC1 = __builtin_amdgcn_mfma_f32_16x16x32_f16(H1[16+s], BF(w2,16+s), aC1,0,0,0);
      }
    }
    floatx4 aB0={b1v,b1v,b1v,b1v}, aB1={0,0,0,0};
    #pragma unroll
    for (int s=0; s<16; ++s){
      aB0 = __builtin_amdgcn_mfma_f32_16x16x32_f16(H0[s],    BF(w1,s),    aB0,0,0,0);
      aB1 = __builtin_amdgcn_mfma_f32_16x16x32_f16(H0[16+s], BF(w1,16+s), aB1,0,0,0);
    }
    {
      floatx4 z1 = (aB0+aB1)+(aC0+aC1);
      gates_store(z1, c1, h1a + (size_t)t*32768, g, c, mt, q, wg);
    }
    __syncthreads();                             // drain h1(t) stores
    if (tid==0) ARRIVE(gcntB, rootB, goB, tA);

    // ---------- slack work: Xacc for iteration t+1 = x(t+2)@Wx0 + b0 ------
    if (t < 511){
      int tn = (t+2 < 512) ? t+2 : 511;
      const _Float16* xb = xh + (size_t)(tn*32 + row)*512 + q*8;
      half8 X[16];
      #pragma unroll
      for (int s=0; s<16; ++s) X[s] = AF(xb, s);
      xA0=(floatx4){b0v,b0v,b0v,b0v}; xA1=(floatx4){0,0,0,0};
      #pragma unroll
      for (int s=0; s<8; ++s){
        xA0 = __builtin_amdgcn_mfma_f32_16x16x32_f16(X[s],   BF(w3,s),   xA0,0,0,0);
        xA1 = __builtin_amdgcn_mfma_f32_16x16x32_f16(X[8+s], BF(w3,8+s), xA1,0,0,0);
      }
    }
  }
}

// ---------------- Y = H1 @ Wd + bd -----------------------------------------
__global__ __launch_bounds__(256) void wd_gemm(const _Float16* __restrict__ h1a,
                                               const _Float16* __restrict__ wda,
                                               const float* __restrict__ bd,
                                               float* __restrict__ y){
  int mb = blockIdx.x;   // 512 blocks of 32 rows (rows = t*32+b)
  int nb = blockIdx.y;   // 4 blocks of 128 cols
  int tid = threadIdx.x, wv = tid>>6, l = tid&63, q = l>>4, c = l&15;
  int mt = wv & 1, nh = wv >> 1;
  floatx4 acc[4];
  #pragma unroll
  for (int gg=0; gg<4; ++gg) acc[gg] = (floatx4){0.f,0.f,0.f,0.f};
  const _Float16* arow = h1a + (size_t)(mb*32 + mt*16 + c)*1024;
  #pragma unroll 4
  for (int ks=0; ks<32; ++ks){
    int kc = ks*4 + q;
    half8 a = *(const half8*)(arow + kc*8);
    #pragma unroll
    for (int gg=0; gg<4; ++gg){
      int nt = nb*8 + nh*4 + gg;
      half8 b = *(const half8*)(wda + ((size_t)(nt*128 + kc)*16 + c)*8);
      acc[gg] = __builtin_amdgcn_mfma_f32_16x16x32_f16(a,b,acc[gg],0,0,0);
    }
  }
  #pragma unroll
  for (int gg=0; gg<4; ++gg){
    int o = nb*128 + nh*64 + gg*16 + c;
    float bdv = bd[o];
    #pragma unroll
    for (int r=0;r<4;++r){
      int row = mb*32 + mt*16 + q*4 + r;
      int tt = row >> 5, bb = row & 31;
      y[(size_t)bb*262144 + tt*512 + o] = acc[gg][r] + bdv;
    }
  }
}

// ---------------------------------------------------------------------------
extern "C" void kernel_launch(void* const* d_in, const int* in_sizes, int n_in,
                              void* d_out, int out_size, void* d_ws, size_t ws_size,
                              hipStream_t stream){
  const float* x   = (const float*)d_in[0];
  const float* Wx0 = (const float*)d_in[1];
  const float* Wh0 = (const float*)d_in[2];
  const float* b0  = (const float*)d_in[3];
  const float* Wx1 = (const float*)d_in[4];
  const float* Wh1 = (const float*)d_in[5];
  const float* b1  = (const float*)d_in[6];
  const float* Wd  = (const float*)d_in[7];
  const float* bd  = (const float*)d_in[8];
  float* y = (float*)d_out;
  char* ws = (char*)d_ws;

  _Float16* wrec = (_Float16*)(ws + WREC_OFF);
  _Float16* wx0a = (_Float16*)(ws + WX0_OFF);
  _Float16* wda  = (_Float16*)(ws + WD_OFF);
  _Float16* xh   = (_Float16*)(ws + XH_OFF);
  _Float16* h1a  = (_Float16*)(ws + H1_OFF);
  _Float16* h0a  = (_Float16*)(ws + H0_OFF);
  unsigned int* flags = (unsigned int*)(ws + FLAGS_OFF);

  hipMemsetAsync(flags, 0, 65536, stream);
  conv_wrec<<<dim3(6144), dim3(256), 0, stream>>>(Wh0, Wx1, Wh1, wrec);
  conv_wx0 <<<dim3(1024), dim3(256), 0, stream>>>(Wx0, wx0a);
  conv_wd  <<<dim3(256),  dim3(256), 0, stream>>>(Wd, wda);
  conv_x   <<<dim3(8192), dim3(256), 0, stream>>>(x, xh);
  hipFuncSetAttribute((const void*)lstm_persist,
                      hipFuncAttributeMaxDynamicSharedMemorySize, 114688);
  lstm_persist<<<dim3(256), dim3(128), 114688, stream>>>(wrec, wx0a, xh, b0, b1,
                                                         h0a, h1a, flags);
  wd_gemm  <<<dim3(512,4), dim3(256), 0, stream>>>(h1a, wda, bd, y);
}

// Round 6
// 5514.945 us; speedup vs baseline: 1.0391x; 1.0391x over previous
//
#include <hip/hip_runtime.h>

// ---------------------------------------------------------------------------
// SimpleLSTM: 2-layer LSTM (B=32,T=512,D=512,H=1024) + output proj (O=512).
//   conv kernels : fp32 -> f16, weights rearranged into MFMA B-frag order
//   zx0_gemm     : Zx0[t][wg][m][c] = x@Wx0 + b0  (parallel over all T)
//   lstm_persist : 256 persistent WGs (1/CU), recurrent weights in LDS
//   wd_gemm      : Y = H1 @ Wd + bd
// R4: tree barrier, 1 barrier/step (22.7 -> 14.5 ms).
// R5: uncached h-exchange stores, direct-from-global A-frags (14.5 -> 8.3).
// R6: poll de-congestion + merged B(t)/A(t+1) phase (8.3 -> 7.6).
// R7: NO FENCES. h1a t-indexed; fresh-line reads need no invalidate (7.6->6.6).
// R8: h0a t-indexed too; all h reads plain cached loads (6.6 -> 5.8).
// R9: flat zero-RMW barrier — REGRESSED; reverted to R8 tree.
// R10: register-batched h loads (64 frags in flight) (5.4 -> 4.8 persist).
// R11: in-loop Wx0 fusion — REGRESSED (tid0's poll start was delayed by the
//     X-GEMM). Reverted; zx0 precompute restored (LLC-thrash theory dead:
//     FETCH/WRITE are structural fan-out/sector terms, not thrash).
// R12: split-phase dual barrier — REGRESSED (+1 syncthreads, +1 tree = +1
//     us/step). Lesson: the loop is latency-ADDITIVE; only overlaps that
//     add NOTHING serial can win.
// R13: two zero-insertion overlaps on the R10 chain:
//     (1) arrive (wave0-lane0) runs CONCURRENT with go-poll (wave1-lane0).
//     (2) gated L2 prefetch: wave1 lanes 1..32 spend the barrier wait
//         polling the two leaf counters covering their 128B line of
//         h0(t)/h1(t-1) (row = wg>>3, colgroup = lane); when both reach
//         8*(t+1) the line is complete at LLC -> one cached touch fills
//         the XCD's L2. 32 WGs/XCD x 32 lanes cover all 1024 lines, so
//         the post-go 128KiB/XCD fill burst is pre-warmed off-path.
// ---------------------------------------------------------------------------

typedef _Float16 half8  __attribute__((ext_vector_type(8)));
typedef float    floatx4 __attribute__((ext_vector_type(4)));

// ws layout (bytes)
#define WREC_OFF   0UL            // [256 wg][3 mat][128 kc][16 c][8] f16 = 24 MiB
#define WX0_OFF    25165824UL     // [256 wg][64 kc][16 c][8] f16        = 4 MiB
#define WD_OFF     29360128UL     // [32 nt][128 kc][16 c][8] f16        = 1 MiB
#define XH_OFF     30408704UL     // [512 t][32 b][512 d] f16            = 16 MiB
#define ZX0_OFF    47185920UL     // [512 t][256 wg][32 m][16 c] f16     = 128 MiB
#define H1_OFF     181403648UL    // [512 t][32 m][1024 k] f16           = 32 MiB
#define H0_OFF     214958080UL    // [512 t][32 m][1024 k] f16           = 32 MiB
#define FLAGS_OFF  248512512UL    // 24 KiB: gcnt[32]@256B, root, go[32]@256B

__device__ __forceinline__ float fsig(float x){ return 1.0f/(1.0f + __expf(-x)); }
__device__ __forceinline__ float ftanhf(float x){
  float e = __expf(2.0f*fabsf(x));
  float r = 1.0f - 2.0f/(e + 1.0f);
  return copysignf(r, x);
}

// ---------------- weight conversion ----------------------------------------
__global__ void conv_wrec(const float* __restrict__ Wh0,
                          const float* __restrict__ Wx1,
                          const float* __restrict__ Wh1,
                          _Float16* __restrict__ out){
  int idx = blockIdx.x*256 + threadIdx.x;          // ((wg*3+mat)*128+kc)*16+c
  if (idx >= 256*3*128*16) return;
  int c  = idx & 15;
  int t1 = idx >> 4;
  int kc = t1 & 127;
  int t2 = t1 >> 7;
  int mat = t2 % 3;
  int wg  = t2 / 3;
  const float* W = (mat==0) ? Wh0 : (mat==1) ? Wx1 : Wh1;
  int col = (c>>2)*1024 + wg*4 + (c&3);
  _Float16* o = out + (size_t)idx*8;
  #pragma unroll
  for (int j=0;j<8;++j) o[j] = (_Float16)W[(kc*8+j)*4096 + col];
}

__global__ void conv_wx0(const float* __restrict__ W, _Float16* __restrict__ out){
  int idx = blockIdx.x*256 + threadIdx.x;          // ((wg*64+kc)*16+c)
  if (idx >= 256*64*16) return;
  int c  = idx & 15;
  int kc = (idx >> 4) & 63;
  int wg = idx >> 10;
  int col = (c>>2)*1024 + wg*4 + (c&3);
  _Float16* o = out + (size_t)idx*8;
  #pragma unroll
  for (int j=0;j<8;++j) o[j] = (_Float16)W[(kc*8+j)*4096 + col];
}

__global__ void conv_wd(const float* __restrict__ W, _Float16* __restrict__ out){
  int idx = blockIdx.x*256 + threadIdx.x;          // ((nt*128+kc)*16+c)
  if (idx >= 32*128*16) return;
  int c  = idx & 15;
  int kc = (idx >> 4) & 127;
  int nt = idx >> 11;
  int col = nt*16 + c;
  _Float16* o = out + (size_t)idx*8;
  #pragma unroll
  for (int j=0;j<8;++j) o[j] = (_Float16)W[(kc*8+j)*512 + col];
}

// x[b][t][d] fp32 -> xh[t*32+b][d] f16  (time-major rows for zx0_gemm)
__global__ void conv_x(const float* __restrict__ x, _Float16* __restrict__ xh){
  int idx = blockIdx.x*256 + threadIdx.x;          // [bt][dq], dq = d/4
  if (idx >= 2097152) return;
  int dq = idx & 127;
  int bt = idx >> 7;          // t*32 + b
  int b  = bt & 31;
  int t  = bt >> 5;
  float4 v = ((const float4*)x)[(size_t)(b*512 + t)*128 + dq];
  _Float16* o = xh + (size_t)idx*4;
  o[0]=(_Float16)v.x; o[1]=(_Float16)v.y; o[2]=(_Float16)v.z; o[3]=(_Float16)v.w;
}

// ---------------- Zx0 = x @ Wx0 + b0 ---------------------------------------
__global__ __launch_bounds__(64) void zx0_gemm(const _Float16* __restrict__ xh,
                                               const _Float16* __restrict__ wx0a,
                                               const float* __restrict__ b0,
                                               _Float16* __restrict__ zx0){
  int t   = blockIdx.x;        // 512
  int wgg = blockIdx.y;        // 64 (covers 4 wg slices)
  int l = threadIdx.x, q = l>>4, c = l&15;
  floatx4 acc[2][4];
  #pragma unroll
  for (int g=0; g<4; ++g){
    int wg = wgg*4+g;
    float bv = b0[(c>>2)*1024 + wg*4 + (c&3)];
    acc[0][g] = (floatx4){bv,bv,bv,bv};
    acc[1][g] = (floatx4){bv,bv,bv,bv};
  }
  #pragma unroll 4
  for (int ks=0; ks<16; ++ks){
    int kc = ks*4 + q;
    half8 a0 = *(const half8*)(xh + (t*32      + c)*512 + kc*8);
    half8 a1 = *(const half8*)(xh + (t*32 + 16 + c)*512 + kc*8);
    #pragma unroll
    for (int g=0; g<4; ++g){
      int wg = wgg*4+g;
      half8 b = *(const half8*)(wx0a + ((size_t)(wg*64 + kc)*16 + c)*8);
      acc[0][g] = __builtin_amdgcn_mfma_f32_16x16x32_f16(a0,b,acc[0][g],0,0,0);
      acc[1][g] = __builtin_amdgcn_mfma_f32_16x16x32_f16(a1,b,acc[1][g],0,0,0);
    }
  }
  #pragma unroll
  for (int g=0; g<4; ++g){
    int wg = wgg*4+g;
    #pragma unroll
    for (int mt=0; mt<2; ++mt)
      #pragma unroll
      for (int r=0;r<4;++r){
        int m = mt*16 + q*4 + r;
        zx0[((size_t)(t*256 + wg)*32 + m)*16 + c] = (_Float16)acc[mt][g][r];
      }
  }
}

// ---------------- persistent recurrent kernel ------------------------------
// LDS: w0 (Wh0), w1 (Wx1), w2 (Wh1): [128 kc][16 c][8] each = 96 KiB total
#define AF(base, ks)  (*(const half8*)((base) + (ks)*32))
#define BF(w, ks)     (*(const half8*)((w) + (((ks)*4 + q)*16 + c)*8))

// gate exchange + cell update + packed agent-scope store of h (cols wg*4..+3)
__device__ __forceinline__ void gates_store(floatx4 acc, float* cs,
    _Float16* dst, int g, int c, int mt, int q, int wg){
  #pragma unroll
  for (int r=0;r<4;++r){
    float v0 = acc[r];
    float v1 = __shfl_xor(v0, 4, 64);
    float v2 = __shfl_xor(v0, 8, 64);
    float v3 = __shfl_xor(v1, 8, 64);
    float zi = (g==0)?v0:(g==1)?v1:(g==2)?v2:v3;
    float zf = (g==0)?v1:(g==1)?v0:(g==2)?v3:v2;
    float zg = (g==0)?v2:(g==1)?v3:(g==2)?v0:v1;
    float zo = (g==0)?v3:(g==1)?v2:(g==2)?v1:v0;
    float cn = fsig(zf)*cs[r] + fsig(zi)*ftanhf(zg);
    cs[r] = cn;
    float hv = fsig(zo)*ftanhf(cn);
    unsigned hb16 = (unsigned)__builtin_bit_cast(unsigned short, (_Float16)hv);
    unsigned up   = (unsigned)__shfl_xor((int)hb16, 1, 64);
    if (g==0 && (c&1)==0)
      __hip_atomic_store((unsigned*)(dst + (mt*16 + q*4 + r)*1024 + wg*4 + c),
                         hb16 | (up<<16),
                         __ATOMIC_RELAXED, __HIP_MEMORY_SCOPE_AGENT);
  }
}

__global__ __launch_bounds__(128, 1) void lstm_persist(
    const _Float16* __restrict__ wrec, const _Float16* __restrict__ zx0,
    const float* __restrict__ b1g, _Float16* __restrict__ h0a,
    _Float16* __restrict__ h1a, unsigned int* __restrict__ flags)
{
  extern __shared__ _Float16 lds[];
  _Float16* w0  = lds;            // 16384 halves
  _Float16* w1  = lds + 16384;
  _Float16* w2  = lds + 32768;

  const int wg = blockIdx.x, tid = threadIdx.x;
  const int wv = tid>>6, l = tid&63, q = l>>4, c = l&15;
  const int g = (c>>2);           // gate of own column
  const int mt = wv;              // wave0 rows 0-15, wave1 rows 16-31
  const int row = mt*16 + c;      // A-frag row this lane loads
  const int grp = wg >> 3;        // 32 groups of 8
  const int slice = (wg >> 3) & 31;  // row this WG prefetch-touches (0..31)

  unsigned int* gcnt = flags + grp*64;        // 256B apart
  unsigned int* root = flags + 2048;          // own line
  unsigned int* go   = flags + 4096;          // go[g2] at 4096 + g2*64

  { // stage this WG's weight slice: 98304 B = 6144 uint4
    const uint4* src = (const uint4*)(wrec + (size_t)wg*49152);
    uint4* dst = (uint4*)lds;
    for (int i=tid; i<6144; i+=128) dst[i] = src[i];
  }
  float c0[4] = {0,0,0,0}, c1[4] = {0,0,0,0};
  const float b1v = b1g[g*1024 + wg*4 + (c&3)];
  __syncthreads();

  // ---------- prologue: A(0): h0(0) = act(Zx0[0]) (h0(-1)=0) ----------
  {
    const _Float16* zsrc = zx0 + ((size_t)wg*32 + mt*16 + q*4)*16 + c;
    floatx4 a;
    a[0]=(float)zsrc[0]; a[1]=(float)zsrc[16]; a[2]=(float)zsrc[32]; a[3]=(float)zsrc[48];
    gates_store(a, c0, h0a, g, c, mt, q, wg);   // t = 0
  }

  for (int t=0; t<512; ++t){
    // prefetch zx0 for A(t+1) (register-resident across the barrier)
    int tn = (t<511) ? t+1 : 511;
    const _Float16* zsrc = zx0 + ((size_t)(tn*256 + wg)*32 + mt*16 + q*4)*16 + c;
    float pz0=(float)zsrc[0], pz1=(float)zsrc[16], pz2=(float)zsrc[32], pz3=(float)zsrc[48];

    __syncthreads();   // drains vmcnt: h0(t)/h1(t-1) stores visible at LLC

    const unsigned tgt = (unsigned)(t+1);
    if (wv == 0){
      // ---------- wave0: barrier arrive (32x8 tree + go broadcast) --------
      if (l == 0){
        unsigned o = __hip_atomic_fetch_add(gcnt, 1u, __ATOMIC_RELAXED,
                                            __HIP_MEMORY_SCOPE_AGENT);
        if (o == 8u*tgt - 1u){
          unsigned r = __hip_atomic_fetch_add(root, 1u, __ATOMIC_RELAXED,
                                              __HIP_MEMORY_SCOPE_AGENT);
          if (r == 32u*tgt - 1u){
            #pragma unroll
            for (int g2=0; g2<32; ++g2)
              __hip_atomic_store(go + g2*64, tgt, __ATOMIC_RELAXED,
                                 __HIP_MEMORY_SCOPE_AGENT);
          }
        }
      }
    } else {
      // ---------- wave1: concurrent poll (lane 0) + gated L2 prefetch -----
      // lanes 1..16: h0(t) line (row=slice, colgroup=l-1)
      // lanes 17..32: h1(t-1) line (row=slice, colgroup=l-17), skip at t=0
      const _Float16* tp = nullptr;
      const unsigned int *ga = nullptr, *gb = nullptr;
      if (l >= 1 && l <= 16){
        int w = l-1;
        tp = h0a + (size_t)t*32768 + slice*1024 + w*64;
        ga = flags + (2*w)*64; gb = flags + (2*w+1)*64;
      } else if (l >= 17 && l <= 32 && t > 0){
        int w = l-17;
        tp = h1a + (size_t)(t-1)*32768 + slice*1024 + w*64;
        ga = flags + (2*w)*64; gb = flags + (2*w+1)*64;
      }
      const unsigned thr = 8u*tgt;
      int done = (tp == nullptr);
      for (;;){
        int gov = 0;
        if (l == 0)
          gov = (int)(__hip_atomic_load(go + grp*64, __ATOMIC_RELAXED,
                                        __HIP_MEMORY_SCOPE_AGENT) >= tgt);
        if (!done){
          unsigned a = __hip_atomic_load(ga, __ATOMIC_RELAXED,
                                         __HIP_MEMORY_SCOPE_AGENT);
          unsigned b = __hip_atomic_load(gb, __ATOMIC_RELAXED,
                                         __HIP_MEMORY_SCOPE_AGENT);
          if (a >= thr && b >= thr){
            // line complete at LLC: cached touch fills this XCD's L2
            unsigned tv;
            asm volatile("global_load_dword %0, %1, off\n\t"
                         "s_waitcnt vmcnt(0)"
                         : "=v"(tv) : "v"(tp) : "memory");
            done = 1;
          }
        }
        if (__shfl(gov, 0, 64)) break;
        __builtin_amdgcn_s_sleep(1);
      }
    }
    __syncthreads();
    // NO acquire fence: h0a[t]/h1a[t-1] lines are fresh by construction
    // (never cached by any XCD before their gated first read; producers
    // stored uncached to LLC). zx0/weights are read-only.

    // ---------- register-batched loads: all 64 fragments in flight --------
    const _Float16* h0c = h0a + (size_t)t*32768 + row*1024 + q*8;
    const _Float16* h1p = h1a + (size_t)(t-1)*32768 + row*1024 + q*8;
    half8 H1[32], H0[32];
    if (t > 0){
      #pragma unroll
      for (int s=0; s<32; ++s) H1[s] = AF(h1p, s);
    }
    #pragma unroll
    for (int s=0; s<32; ++s) H0[s] = AF(h0c, s);

    // ---------- merged compute: B(t) and A(t+1) ----------
    floatx4 aA0={0,0,0,0}, aA1={0,0,0,0};
    floatx4 aB0={b1v,b1v,b1v,b1v}, aB1={0,0,0,0};
    floatx4 aC0={0,0,0,0}, aC1={0,0,0,0};
    if (t > 0){
      #pragma unroll
      for (int s=0; s<16; ++s){
        aC0 = __builtin_amdgcn_mfma_f32_16x16x32_f16(H1[s],    BF(w2,s),    aC0,0,0,0);
        aC1 = __builtin_amdgcn_mfma_f32_16x16x32_f16(H1[16+s], BF(w2,16+s), aC1,0,0,0);
      }
    }
    #pragma unroll
    for (int s=0; s<16; ++s){
      aB0 = __builtin_amdgcn_mfma_f32_16x16x32_f16(H0[s],    BF(w1,s),    aB0,0,0,0);
      aB1 = __builtin_amdgcn_mfma_f32_16x16x32_f16(H0[16+s], BF(w1,16+s), aB1,0,0,0);
      aA0 = __builtin_amdgcn_mfma_f32_16x16x32_f16(H0[s],    BF(w0,s),    aA0,0,0,0);
      aA1 = __builtin_amdgcn_mfma_f32_16x16x32_f16(H0[16+s], BF(w0,16+s), aA1,0,0,0);
    }
    // B(t): h1(t)
    {
      floatx4 z1 = (aB0+aB1)+(aC0+aC1);
      gates_store(z1, c1, h1a + (size_t)t*32768, g, c, mt, q, wg);
    }
    // A(t+1): h0(t+1)
    if (t < 511){
      floatx4 z0 = aA0+aA1;
      z0[0]+=pz0; z0[1]+=pz1; z0[2]+=pz2; z0[3]+=pz3;
      gates_store(z0, c0, h0a + (size_t)(t+1)*32768, g, c, mt, q, wg);
    }
  }
}

// ---------------- Y = H1 @ Wd + bd -----------------------------------------
__global__ __launch_bounds__(256) void wd_gemm(const _Float16* __restrict__ h1a,
                                               const _Float16* __restrict__ wda,
                                               const float* __restrict__ bd,
                                               float* __restrict__ y){
  int mb = blockIdx.x;   // 512 blocks of 32 rows (rows = t*32+b)
  int nb = blockIdx.y;   // 4 blocks of 128 cols
  int tid = threadIdx.x, wv = tid>>6, l = tid&63, q = l>>4, c = l&15;
  int mt = wv & 1, nh = wv >> 1;
  floatx4 acc[4];
  #pragma unroll
  for (int gg=0; gg<4; ++gg) acc[gg] = (floatx4){0.f,0.f,0.f,0.f};
  const _Float16* arow = h1a + (size_t)(mb*32 + mt*16 + c)*1024;
  #pragma unroll 4
  for (int ks=0; ks<32; ++ks){
    int kc = ks*4 + q;
    half8 a = *(const half8*)(arow + kc*8);
    #pragma unroll
    for (int gg=0; gg<4; ++gg){
      int nt = nb*8 + nh*4 + gg;
      half8 b = *(const half8*)(wda + ((size_t)(nt*128 + kc)*16 + c)*8);
      acc[gg] = __builtin_amdgcn_mfma_f32_16x16x32_f16(a,b,acc[gg],0,0,0);
    }
  }
  #pragma unroll
  for (int gg=0; gg<4; ++gg){
    int o = nb*128 + nh*64 + gg*16 + c;
    float bdv = bd[o];
    #pragma unroll
    for (int r=0;r<4;++r){
      int row = mb*32 + mt*16 + q*4 + r;
      int tt = row >> 5, bb = row & 31;
      y[(size_t)bb*262144 + tt*512 + o] = acc[gg][r] + bdv;
    }
  }
}

// ---------------------------------------------------------------------------
extern "C" void kernel_launch(void* const* d_in, const int* in_sizes, int n_in,
                              void* d_out, int out_size, void* d_ws, size_t ws_size,
                              hipStream_t stream){
  const float* x   = (const float*)d_in[0];
  const float* Wx0 = (const float*)d_in[1];
  const float* Wh0 = (const float*)d_in[2];
  const float* b0  = (const float*)d_in[3];
  const float* Wx1 = (const float*)d_in[4];
  const float* Wh1 = (const float*)d_in[5];
  const float* b1  = (const float*)d_in[6];
  const float* Wd  = (const float*)d_in[7];
  const float* bd  = (const float*)d_in[8];
  float* y = (float*)d_out;
  char* ws = (char*)d_ws;

  _Float16* wrec = (_Float16*)(ws + WREC_OFF);
  _Float16* wx0a = (_Float16*)(ws + WX0_OFF);
  _Float16* wda  = (_Float16*)(ws + WD_OFF);
  _Float16* xh   = (_Float16*)(ws + XH_OFF);
  _Float16* zx0  = (_Float16*)(ws + ZX0_OFF);
  _Float16* h1a  = (_Float16*)(ws + H1_OFF);
  _Float16* h0a  = (_Float16*)(ws + H0_OFF);
  unsigned int* flags = (unsigned int*)(ws + FLAGS_OFF);

  hipMemsetAsync(flags, 0, 24576, stream);
  conv_wrec<<<dim3(6144), dim3(256), 0, stream>>>(Wh0, Wx1, Wh1, wrec);
  conv_wx0 <<<dim3(1024), dim3(256), 0, stream>>>(Wx0, wx0a);
  conv_wd  <<<dim3(256),  dim3(256), 0, stream>>>(Wd, wda);
  conv_x   <<<dim3(8192), dim3(256), 0, stream>>>(x, xh);
  zx0_gemm <<<dim3(512,64), dim3(64), 0, stream>>>(xh, wx0a, b0, zx0);
  hipFuncSetAttribute((const void*)lstm_persist,
                      hipFuncAttributeMaxDynamicSharedMemorySize, 98304);
  lstm_persist<<<dim3(256), dim3(128), 98304, stream>>>(wrec, zx0, b1, h0a, h1a, flags);
  wd_gemm  <<<dim3(512,4), dim3(256), 0, stream>>>(h1a, wda, bd, y);
}

// Round 7
// 5306.550 us; speedup vs baseline: 1.0799x; 1.0393x over previous
//
#include <hip/hip_runtime.h>

// ---------------------------------------------------------------------------
// SimpleLSTM: 2-layer LSTM (B=32,T=512,D=512,H=1024) + output proj (O=512).
//   conv kernels : fp32 -> f16, weights rearranged into MFMA B-frag order
//   zx0_gemm     : Zx0[t][wg][m][c] = x@Wx0 + b0  (parallel over all T)
//   lstm_persist : 256 persistent WGs (1/CU), recurrent weights in LDS
//   wd_gemm      : Y = H1 @ Wd + bd
// R4: tree barrier, 1 barrier/step (22.7 -> 14.5 ms).
// R5: uncached h-exchange stores, direct-from-global A-frags (14.5 -> 8.3).
// R6: poll de-congestion + merged B(t)/A(t+1) phase (8.3 -> 7.6).
// R7: NO FENCES. h1a t-indexed; fresh-line reads need no invalidate (7.6->6.6).
// R8: h0a t-indexed too; all h reads plain cached loads (6.6 -> 5.8).
// R9: flat zero-RMW barrier — REGRESSED; reverted.
// R10: register-batched h loads (64 frags in flight) (5.4 -> 4.8 persist).
// R11: in-loop Wx0 fusion — REGRESSED; reverted (zx0 precompute restored).
// R12: split-phase dual barrier — REGRESSED (+1 sync, +1 tree).
// R13: gated L2 prefetch during wait — REGRESSED (poll overhead > benefit).
// R14: HOP-COUNT REDUCTION on the R10 chain (nothing added, two hops cut):
//     (a) barrier = leaf arrive + WAVE-PARALLEL DIRECT POLL. wave0 lane l
//         polls leaf counter gcnt[l] until >= 8*(t+1); __ballot consensus.
//         Deletes the root RMW (32 serialized RMWs on one line), the
//         32-store broadcast, and the go-line poll hop — detection is one
//         parallel read round on 32 lines.
//     (b) zx0 prefetch moved AFTER the leaf arrive: its LLC/HBM latency
//         (~0.3-0.4us) no longer sits inside the pre-barrier vmcnt drain;
//         it completes in the shadow of the poll wait.
// ---------------------------------------------------------------------------

typedef _Float16 half8  __attribute__((ext_vector_type(8)));
typedef float    floatx4 __attribute__((ext_vector_type(4)));

// ws layout (bytes)
#define WREC_OFF   0UL            // [256 wg][3 mat][128 kc][16 c][8] f16 = 24 MiB
#define WX0_OFF    25165824UL     // [256 wg][64 kc][16 c][8] f16        = 4 MiB
#define WD_OFF     29360128UL     // [32 nt][128 kc][16 c][8] f16        = 1 MiB
#define XH_OFF     30408704UL     // [512 t][32 b][512 d] f16            = 16 MiB
#define ZX0_OFF    47185920UL     // [512 t][256 wg][32 m][16 c] f16     = 128 MiB
#define H1_OFF     181403648UL    // [512 t][32 m][1024 k] f16           = 32 MiB
#define H0_OFF     214958080UL    // [512 t][32 m][1024 k] f16           = 32 MiB
#define FLAGS_OFF  248512512UL    // 24 KiB: gcnt[32] at 256B stride

__device__ __forceinline__ float fsig(float x){ return 1.0f/(1.0f + __expf(-x)); }
__device__ __forceinline__ float ftanhf(float x){
  float e = __expf(2.0f*fabsf(x));
  float r = 1.0f - 2.0f/(e + 1.0f);
  return copysignf(r, x);
}

// ---------------- weight conversion ----------------------------------------
__global__ void conv_wrec(const float* __restrict__ Wh0,
                          const float* __restrict__ Wx1,
                          const float* __restrict__ Wh1,
                          _Float16* __restrict__ out){
  int idx = blockIdx.x*256 + threadIdx.x;          // ((wg*3+mat)*128+kc)*16+c
  if (idx >= 256*3*128*16) return;
  int c  = idx & 15;
  int t1 = idx >> 4;
  int kc = t1 & 127;
  int t2 = t1 >> 7;
  int mat = t2 % 3;
  int wg  = t2 / 3;
  const float* W = (mat==0) ? Wh0 : (mat==1) ? Wx1 : Wh1;
  int col = (c>>2)*1024 + wg*4 + (c&3);
  _Float16* o = out + (size_t)idx*8;
  #pragma unroll
  for (int j=0;j<8;++j) o[j] = (_Float16)W[(kc*8+j)*4096 + col];
}

__global__ void conv_wx0(const float* __restrict__ W, _Float16* __restrict__ out){
  int idx = blockIdx.x*256 + threadIdx.x;          // ((wg*64+kc)*16+c)
  if (idx >= 256*64*16) return;
  int c  = idx & 15;
  int kc = (idx >> 4) & 63;
  int wg = idx >> 10;
  int col = (c>>2)*1024 + wg*4 + (c&3);
  _Float16* o = out + (size_t)idx*8;
  #pragma unroll
  for (int j=0;j<8;++j) o[j] = (_Float16)W[(kc*8+j)*4096 + col];
}

__global__ void conv_wd(const float* __restrict__ W, _Float16* __restrict__ out){
  int idx = blockIdx.x*256 + threadIdx.x;          // ((nt*128+kc)*16+c)
  if (idx >= 32*128*16) return;
  int c  = idx & 15;
  int kc = (idx >> 4) & 127;
  int nt = idx >> 11;
  int col = nt*16 + c;
  _Float16* o = out + (size_t)idx*8;
  #pragma unroll
  for (int j=0;j<8;++j) o[j] = (_Float16)W[(kc*8+j)*512 + col];
}

// x[b][t][d] fp32 -> xh[t*32+b][d] f16  (time-major rows for zx0_gemm)
__global__ void conv_x(const float* __restrict__ x, _Float16* __restrict__ xh){
  int idx = blockIdx.x*256 + threadIdx.x;          // [bt][dq], dq = d/4
  if (idx >= 2097152) return;
  int dq = idx & 127;
  int bt = idx >> 7;          // t*32 + b
  int b  = bt & 31;
  int t  = bt >> 5;
  float4 v = ((const float4*)x)[(size_t)(b*512 + t)*128 + dq];
  _Float16* o = xh + (size_t)idx*4;
  o[0]=(_Float16)v.x; o[1]=(_Float16)v.y; o[2]=(_Float16)v.z; o[3]=(_Float16)v.w;
}

// ---------------- Zx0 = x @ Wx0 + b0 ---------------------------------------
__global__ __launch_bounds__(64) void zx0_gemm(const _Float16* __restrict__ xh,
                                               const _Float16* __restrict__ wx0a,
                                               const float* __restrict__ b0,
                                               _Float16* __restrict__ zx0){
  int t   = blockIdx.x;        // 512
  int wgg = blockIdx.y;        // 64 (covers 4 wg slices)
  int l = threadIdx.x, q = l>>4, c = l&15;
  floatx4 acc[2][4];
  #pragma unroll
  for (int g=0; g<4; ++g){
    int wg = wgg*4+g;
    float bv = b0[(c>>2)*1024 + wg*4 + (c&3)];
    acc[0][g] = (floatx4){bv,bv,bv,bv};
    acc[1][g] = (floatx4){bv,bv,bv,bv};
  }
  #pragma unroll 4
  for (int ks=0; ks<16; ++ks){
    int kc = ks*4 + q;
    half8 a0 = *(const half8*)(xh + (t*32      + c)*512 + kc*8);
    half8 a1 = *(const half8*)(xh + (t*32 + 16 + c)*512 + kc*8);
    #pragma unroll
    for (int g=0; g<4; ++g){
      int wg = wgg*4+g;
      half8 b = *(const half8*)(wx0a + ((size_t)(wg*64 + kc)*16 + c)*8);
      acc[0][g] = __builtin_amdgcn_mfma_f32_16x16x32_f16(a0,b,acc[0][g],0,0,0);
      acc[1][g] = __builtin_amdgcn_mfma_f32_16x16x32_f16(a1,b,acc[1][g],0,0,0);
    }
  }
  #pragma unroll
  for (int g=0; g<4; ++g){
    int wg = wgg*4+g;
    #pragma unroll
    for (int mt=0; mt<2; ++mt)
      #pragma unroll
      for (int r=0;r<4;++r){
        int m = mt*16 + q*4 + r;
        zx0[((size_t)(t*256 + wg)*32 + m)*16 + c] = (_Float16)acc[mt][g][r];
      }
  }
}

// ---------------- persistent recurrent kernel ------------------------------
// LDS: w0 (Wh0), w1 (Wx1), w2 (Wh1): [128 kc][16 c][8] each = 96 KiB total
#define AF(base, ks)  (*(const half8*)((base) + (ks)*32))
#define BF(w, ks)     (*(const half8*)((w) + (((ks)*4 + q)*16 + c)*8))

// gate exchange + cell update + packed agent-scope store of h (cols wg*4..+3)
__device__ __forceinline__ void gates_store(floatx4 acc, float* cs,
    _Float16* dst, int g, int c, int mt, int q, int wg){
  #pragma unroll
  for (int r=0;r<4;++r){
    float v0 = acc[r];
    float v1 = __shfl_xor(v0, 4, 64);
    float v2 = __shfl_xor(v0, 8, 64);
    float v3 = __shfl_xor(v1, 8, 64);
    float zi = (g==0)?v0:(g==1)?v1:(g==2)?v2:v3;
    float zf = (g==0)?v1:(g==1)?v0:(g==2)?v3:v2;
    float zg = (g==0)?v2:(g==1)?v3:(g==2)?v0:v1;
    float zo = (g==0)?v3:(g==1)?v2:(g==2)?v1:v0;
    float cn = fsig(zf)*cs[r] + fsig(zi)*ftanhf(zg);
    cs[r] = cn;
    float hv = fsig(zo)*ftanhf(cn);
    unsigned hb16 = (unsigned)__builtin_bit_cast(unsigned short, (_Float16)hv);
    unsigned up   = (unsigned)__shfl_xor((int)hb16, 1, 64);
    if (g==0 && (c&1)==0)
      __hip_atomic_store((unsigned*)(dst + (mt*16 + q*4 + r)*1024 + wg*4 + c),
                         hb16 | (up<<16),
                         __ATOMIC_RELAXED, __HIP_MEMORY_SCOPE_AGENT);
  }
}

__global__ __launch_bounds__(128, 1) void lstm_persist(
    const _Float16* __restrict__ wrec, const _Float16* __restrict__ zx0,
    const float* __restrict__ b1g, _Float16* __restrict__ h0a,
    _Float16* __restrict__ h1a, unsigned int* __restrict__ flags)
{
  extern __shared__ _Float16 lds[];
  _Float16* w0  = lds;            // 16384 halves
  _Float16* w1  = lds + 16384;
  _Float16* w2  = lds + 32768;

  const int wg = blockIdx.x, tid = threadIdx.x;
  const int wv = tid>>6, l = tid&63, q = l>>4, c = l&15;
  const int g = (c>>2);           // gate of own column
  const int mt = wv;              // wave0 rows 0-15, wave1 rows 16-31
  const int row = mt*16 + c;      // A-frag row this lane loads
  const int grp = wg >> 3;        // 32 groups of 8

  unsigned int* gcnt = flags + grp*64;        // this WG's leaf line (256B apart)

  { // stage this WG's weight slice: 98304 B = 6144 uint4
    const uint4* src = (const uint4*)(wrec + (size_t)wg*49152);
    uint4* dst = (uint4*)lds;
    for (int i=tid; i<6144; i+=128) dst[i] = src[i];
  }
  float c0[4] = {0,0,0,0}, c1[4] = {0,0,0,0};
  const float b1v = b1g[g*1024 + wg*4 + (c&3)];
  __syncthreads();

  // ---------- prologue: A(0): h0(0) = act(Zx0[0]) (h0(-1)=0) ----------
  {
    const _Float16* zsrc = zx0 + ((size_t)wg*32 + mt*16 + q*4)*16 + c;
    floatx4 a;
    a[0]=(float)zsrc[0]; a[1]=(float)zsrc[16]; a[2]=(float)zsrc[32]; a[3]=(float)zsrc[48];
    gates_store(a, c0, h0a, g, c, mt, q, wg);   // t = 0
  }

  for (int t=0; t<512; ++t){
    __syncthreads();   // drains vmcnt: h0(t)/h1(t-1) stores visible at LLC

    // ---------- barrier: leaf arrive + wave-parallel direct poll ----------
    const unsigned tgt = (unsigned)(t+1);
    if (tid == 0)
      __hip_atomic_fetch_add(gcnt, 1u, __ATOMIC_RELAXED,
                             __HIP_MEMORY_SCOPE_AGENT);

    // zx0 prefetch for A(t+1): issued after arrive, completes during wait
    int tn = (t<511) ? t+1 : 511;
    const _Float16* zsrc = zx0 + ((size_t)(tn*256 + wg)*32 + mt*16 + q*4)*16 + c;
    float pz0=(float)zsrc[0], pz1=(float)zsrc[16], pz2=(float)zsrc[32], pz3=(float)zsrc[48];

    if (wv == 0){
      const unsigned thr = 8u*tgt;
      const unsigned int* myleaf = flags + l*64;     // lane l -> leaf line l
      for (;;){
        unsigned v = 0xffffffffu;
        if (l < 32)
          v = __hip_atomic_load(myleaf, __ATOMIC_RELAXED,
                                __HIP_MEMORY_SCOPE_AGENT);
        if (__ballot(v >= thr) == 0xffffffffffffffffULL) break;
        __builtin_amdgcn_s_sleep(1);
      }
    }
    __syncthreads();
    // NO acquire fence: h0a[t]/h1a[t-1] lines are fresh by construction
    // (never cached by any XCD before this read; producers stored uncached
    // to LLC). zx0/weights are read-only; __syncthreads orders compiler+HW.

    // ---------- register-batched loads: all 64 fragments in flight --------
    const _Float16* h0c = h0a + (size_t)t*32768 + row*1024 + q*8;
    const _Float16* h1p = h1a + (size_t)(t-1)*32768 + row*1024 + q*8;
    half8 H1[32], H0[32];
    if (t > 0){
      #pragma unroll
      for (int s=0; s<32; ++s) H1[s] = AF(h1p, s);
    }
    #pragma unroll
    for (int s=0; s<32; ++s) H0[s] = AF(h0c, s);

    // ---------- merged compute: B(t) and A(t+1) ----------
    floatx4 aA0={0,0,0,0}, aA1={0,0,0,0};
    floatx4 aB0={b1v,b1v,b1v,b1v}, aB1={0,0,0,0};
    floatx4 aC0={0,0,0,0}, aC1={0,0,0,0};
    if (t > 0){
      #pragma unroll
      for (int s=0; s<16; ++s){
        aC0 = __builtin_amdgcn_mfma_f32_16x16x32_f16(H1[s],    BF(w2,s),    aC0,0,0,0);
        aC1 = __builtin_amdgcn_mfma_f32_16x16x32_f16(H1[16+s], BF(w2,16+s), aC1,0,0,0);
      }
    }
    #pragma unroll
    for (int s=0; s<16; ++s){
      aB0 = __builtin_amdgcn_mfma_f32_16x16x32_f16(H0[s],    BF(w1,s),    aB0,0,0,0);
      aB1 = __builtin_amdgcn_mfma_f32_16x16x32_f16(H0[16+s], BF(w1,16+s), aB1,0,0,0);
      aA0 = __builtin_amdgcn_mfma_f32_16x16x32_f16(H0[s],    BF(w0,s),    aA0,0,0,0);
      aA1 = __builtin_amdgcn_mfma_f32_16x16x32_f16(H0[16+s], BF(w0,16+s), aA1,0,0,0);
    }
    // B(t): h1(t)
    {
      floatx4 z1 = (aB0+aB1)+(aC0+aC1);
      gates_store(z1, c1, h1a + (size_t)t*32768, g, c, mt, q, wg);
    }
    // A(t+1): h0(t+1)
    if (t < 511){
      floatx4 z0 = aA0+aA1;
      z0[0]+=pz0; z0[1]+=pz1; z0[2]+=pz2; z0[3]+=pz3;
      gates_store(z0, c0, h0a + (size_t)(t+1)*32768, g, c, mt, q, wg);
    }
  }
}

// ---------------- Y = H1 @ Wd + bd -----------------------------------------
__global__ __launch_bounds__(256) void wd_gemm(const _Float16* __restrict__ h1a,
                                               const _Float16* __restrict__ wda,
                                               const float* __restrict__ bd,
                                               float* __restrict__ y){
  int mb = blockIdx.x;   // 512 blocks of 32 rows (rows = t*32+b)
  int nb = blockIdx.y;   // 4 blocks of 128 cols
  int tid = threadIdx.x, wv = tid>>6, l = tid&63, q = l>>4, c = l&15;
  int mt = wv & 1, nh = wv >> 1;
  floatx4 acc[4];
  #pragma unroll
  for (int gg=0; gg<4; ++gg) acc[gg] = (floatx4){0.f,0.f,0.f,0.f};
  const _Float16* arow = h1a + (size_t)(mb*32 + mt*16 + c)*1024;
  #pragma unroll 4
  for (int ks=0; ks<32; ++ks){
    int kc = ks*4 + q;
    half8 a = *(const half8*)(arow + kc*8);
    #pragma unroll
    for (int gg=0; gg<4; ++gg){
      int nt = nb*8 + nh*4 + gg;
      half8 b = *(const half8*)(wda + ((size_t)(nt*128 + kc)*16 + c)*8);
      acc[gg] = __builtin_amdgcn_mfma_f32_16x16x32_f16(a,b,acc[gg],0,0,0);
    }
  }
  #pragma unroll
  for (int gg=0; gg<4; ++gg){
    int o = nb*128 + nh*64 + gg*16 + c;
    float bdv = bd[o];
    #pragma unroll
    for (int r=0;r<4;++r){
      int row = mb*32 + mt*16 + q*4 + r;
      int tt = row >> 5, bb = row & 31;
      y[(size_t)bb*262144 + tt*512 + o] = acc[gg][r] + bdv;
    }
  }
}

// ---------------------------------------------------------------------------
extern "C" void kernel_launch(void* const* d_in, const int* in_sizes, int n_in,
                              void* d_out, int out_size, void* d_ws, size_t ws_size,
                              hipStream_t stream){
  const float* x   = (const float*)d_in[0];
  const float* Wx0 = (const float*)d_in[1];
  const float* Wh0 = (const float*)d_in[2];
  const float* b0  = (const float*)d_in[3];
  const float* Wx1 = (const float*)d_in[4];
  const float* Wh1 = (const float*)d_in[5];
  const float* b1  = (const float*)d_in[6];
  const float* Wd  = (const float*)d_in[7];
  const float* bd  = (const float*)d_in[8];
  float* y = (float*)d_out;
  char* ws = (char*)d_ws;

  _Float16* wrec = (_Float16*)(ws + WREC_OFF);
  _Float16* wx0a = (_Float16*)(ws + WX0_OFF);
  _Float16* wda  = (_Float16*)(ws + WD_OFF);
  _Float16* xh   = (_Float16*)(ws + XH_OFF);
  _Float16* zx0  = (_Float16*)(ws + ZX0_OFF);
  _Float16* h1a  = (_Float16*)(ws + H1_OFF);
  _Float16* h0a  = (_Float16*)(ws + H0_OFF);
  unsigned int* flags = (unsigned int*)(ws + FLAGS_OFF);

  hipMemsetAsync(flags, 0, 24576, stream);
  conv_wrec<<<dim3(6144), dim3(256), 0, stream>>>(Wh0, Wx1, Wh1, wrec);
  conv_wx0 <<<dim3(1024), dim3(256), 0, stream>>>(Wx0, wx0a);
  conv_wd  <<<dim3(256),  dim3(256), 0, stream>>>(Wd, wda);
  conv_x   <<<dim3(8192), dim3(256), 0, stream>>>(x, xh);
  zx0_gemm <<<dim3(512,64), dim3(64), 0, stream>>>(xh, wx0a, b0, zx0);
  hipFuncSetAttribute((const void*)lstm_persist,
                      hipFuncAttributeMaxDynamicSharedMemorySize, 98304);
  lstm_persist<<<dim3(256), dim3(128), 98304, stream>>>(wrec, zx0, b1, h0a, h1a, flags);
  wd_gemm  <<<dim3(512,4), dim3(256), 0, stream>>>(h1a, wda, bd, y);
}

// Round 8
// 5074.791 us; speedup vs baseline: 1.1292x; 1.0457x over previous
//
#include <hip/hip_runtime.h>

// ---------------------------------------------------------------------------
// SimpleLSTM: 2-layer LSTM (B=32,T=512,D=512,H=1024) + output proj (O=512).
//   conv kernels : fp32 -> f16, weights rearranged into MFMA B-frag order
//   zx0_gemm     : Zx0[t][wg][m][c] = x@Wx0 + b0  (parallel over all T)
//   lstm_persist : 256 persistent WGs (1/CU), recurrent weights in LDS
//   wd_gemm      : Y = H1 @ Wd + bd
// R4: tree barrier, 1 barrier/step (22.7 -> 14.5 ms).
// R5: uncached h-exchange stores, direct-from-global A-frags (14.5 -> 8.3).
// R6: poll de-congestion + merged B(t)/A(t+1) phase (8.3 -> 7.6).
// R7: NO FENCES. h1a t-indexed; fresh-line reads need no invalidate (7.6->6.6).
// R8: h0a t-indexed too; all h reads plain cached loads (6.6 -> 5.8).
// R9: flat zero-RMW barrier — REGRESSED; reverted.
// R10: register-batched h loads (64 frags in flight) (5.4 -> 4.8 persist).
// R11: in-loop Wx0 fusion — REGRESSED; reverted (zx0 precompute restored).
// R12: split-phase dual barrier — REGRESSED (+1 sync, +1 tree).
// R13: gated L2 prefetch during wait — REGRESSED (poll overhead > benefit).
// R14: direct 32-line wave-poll — REGRESSED (8192 pollers congested the
//     leaf lines the arrivals RMW). Lesson: line congestion >> hop count.
// R15: PARALLEL RELEASE, PRIVATE GO LINES, on the exact R10 chain:
//     (a) root detection is shfl'd to the root WG's whole wave0, which
//         issues all 256 go stores in PARALLEL (4/lane) instead of 32
//         serial stores from one lane — one store-latency, tight landing.
//     (b) go lines are PRIVATE per WG (1 writer, 1 poller each; 64 KiB),
//         poll is a tight loop (no s_sleep) — detection ~1 LLC RTT,
//         minimal jitter, zero line sharing (R14's lesson inverted).
//     Arrive tree, load batching, zx0 placement: byte-identical to R10.
// ---------------------------------------------------------------------------

typedef _Float16 half8  __attribute__((ext_vector_type(8)));
typedef float    floatx4 __attribute__((ext_vector_type(4)));

// ws layout (bytes)
#define WREC_OFF   0UL            // [256 wg][3 mat][128 kc][16 c][8] f16 = 24 MiB
#define WX0_OFF    25165824UL     // [256 wg][64 kc][16 c][8] f16        = 4 MiB
#define WD_OFF     29360128UL     // [32 nt][128 kc][16 c][8] f16        = 1 MiB
#define XH_OFF     30408704UL     // [512 t][32 b][512 d] f16            = 16 MiB
#define ZX0_OFF    47185920UL     // [512 t][256 wg][32 m][16 c] f16     = 128 MiB
#define H1_OFF     181403648UL    // [512 t][32 m][1024 k] f16           = 32 MiB
#define H0_OFF     214958080UL    // [512 t][32 m][1024 k] f16           = 32 MiB
#define FLAGS_OFF  248512512UL    // 80 KiB: gcnt[32]@256B, root@8K, go[256]@16K

__device__ __forceinline__ float fsig(float x){ return 1.0f/(1.0f + __expf(-x)); }
__device__ __forceinline__ float ftanhf(float x){
  float e = __expf(2.0f*fabsf(x));
  float r = 1.0f - 2.0f/(e + 1.0f);
  return copysignf(r, x);
}

// ---------------- weight conversion ----------------------------------------
__global__ void conv_wrec(const float* __restrict__ Wh0,
                          const float* __restrict__ Wx1,
                          const float* __restrict__ Wh1,
                          _Float16* __restrict__ out){
  int idx = blockIdx.x*256 + threadIdx.x;          // ((wg*3+mat)*128+kc)*16+c
  if (idx >= 256*3*128*16) return;
  int c  = idx & 15;
  int t1 = idx >> 4;
  int kc = t1 & 127;
  int t2 = t1 >> 7;
  int mat = t2 % 3;
  int wg  = t2 / 3;
  const float* W = (mat==0) ? Wh0 : (mat==1) ? Wx1 : Wh1;
  int col = (c>>2)*1024 + wg*4 + (c&3);
  _Float16* o = out + (size_t)idx*8;
  #pragma unroll
  for (int j=0;j<8;++j) o[j] = (_Float16)W[(kc*8+j)*4096 + col];
}

__global__ void conv_wx0(const float* __restrict__ W, _Float16* __restrict__ out){
  int idx = blockIdx.x*256 + threadIdx.x;          // ((wg*64+kc)*16+c)
  if (idx >= 256*64*16) return;
  int c  = idx & 15;
  int kc = (idx >> 4) & 63;
  int wg = idx >> 10;
  int col = (c>>2)*1024 + wg*4 + (c&3);
  _Float16* o = out + (size_t)idx*8;
  #pragma unroll
  for (int j=0;j<8;++j) o[j] = (_Float16)W[(kc*8+j)*4096 + col];
}

__global__ void conv_wd(const float* __restrict__ W, _Float16* __restrict__ out){
  int idx = blockIdx.x*256 + threadIdx.x;          // ((nt*128+kc)*16+c)
  if (idx >= 32*128*16) return;
  int c  = idx & 15;
  int kc = (idx >> 4) & 127;
  int nt = idx >> 11;
  int col = nt*16 + c;
  _Float16* o = out + (size_t)idx*8;
  #pragma unroll
  for (int j=0;j<8;++j) o[j] = (_Float16)W[(kc*8+j)*512 + col];
}

// x[b][t][d] fp32 -> xh[t*32+b][d] f16  (time-major rows for zx0_gemm)
__global__ void conv_x(const float* __restrict__ x, _Float16* __restrict__ xh){
  int idx = blockIdx.x*256 + threadIdx.x;          // [bt][dq], dq = d/4
  if (idx >= 2097152) return;
  int dq = idx & 127;
  int bt = idx >> 7;          // t*32 + b
  int b  = bt & 31;
  int t  = bt >> 5;
  float4 v = ((const float4*)x)[(size_t)(b*512 + t)*128 + dq];
  _Float16* o = xh + (size_t)idx*4;
  o[0]=(_Float16)v.x; o[1]=(_Float16)v.y; o[2]=(_Float16)v.z; o[3]=(_Float16)v.w;
}

// ---------------- Zx0 = x @ Wx0 + b0 ---------------------------------------
__global__ __launch_bounds__(64) void zx0_gemm(const _Float16* __restrict__ xh,
                                               const _Float16* __restrict__ wx0a,
                                               const float* __restrict__ b0,
                                               _Float16* __restrict__ zx0){
  int t   = blockIdx.x;        // 512
  int wgg = blockIdx.y;        // 64 (covers 4 wg slices)
  int l = threadIdx.x, q = l>>4, c = l&15;
  floatx4 acc[2][4];
  #pragma unroll
  for (int g=0; g<4; ++g){
    int wg = wgg*4+g;
    float bv = b0[(c>>2)*1024 + wg*4 + (c&3)];
    acc[0][g] = (floatx4){bv,bv,bv,bv};
    acc[1][g] = (floatx4){bv,bv,bv,bv};
  }
  #pragma unroll 4
  for (int ks=0; ks<16; ++ks){
    int kc = ks*4 + q;
    half8 a0 = *(const half8*)(xh + (t*32      + c)*512 + kc*8);
    half8 a1 = *(const half8*)(xh + (t*32 + 16 + c)*512 + kc*8);
    #pragma unroll
    for (int g=0; g<4; ++g){
      int wg = wgg*4+g;
      half8 b = *(const half8*)(wx0a + ((size_t)(wg*64 + kc)*16 + c)*8);
      acc[0][g] = __builtin_amdgcn_mfma_f32_16x16x32_f16(a0,b,acc[0][g],0,0,0);
      acc[1][g] = __builtin_amdgcn_mfma_f32_16x16x32_f16(a1,b,acc[1][g],0,0,0);
    }
  }
  #pragma unroll
  for (int g=0; g<4; ++g){
    int wg = wgg*4+g;
    #pragma unroll
    for (int mt=0; mt<2; ++mt)
      #pragma unroll
      for (int r=0;r<4;++r){
        int m = mt*16 + q*4 + r;
        zx0[((size_t)(t*256 + wg)*32 + m)*16 + c] = (_Float16)acc[mt][g][r];
      }
  }
}

// ---------------- persistent recurrent kernel ------------------------------
// LDS: w0 (Wh0), w1 (Wx1), w2 (Wh1): [128 kc][16 c][8] each = 96 KiB total
#define AF(base, ks)  (*(const half8*)((base) + (ks)*32))
#define BF(w, ks)     (*(const half8*)((w) + (((ks)*4 + q)*16 + c)*8))

// gate exchange + cell update + packed agent-scope store of h (cols wg*4..+3)
__device__ __forceinline__ void gates_store(floatx4 acc, float* cs,
    _Float16* dst, int g, int c, int mt, int q, int wg){
  #pragma unroll
  for (int r=0;r<4;++r){
    float v0 = acc[r];
    float v1 = __shfl_xor(v0, 4, 64);
    float v2 = __shfl_xor(v0, 8, 64);
    float v3 = __shfl_xor(v1, 8, 64);
    float zi = (g==0)?v0:(g==1)?v1:(g==2)?v2:v3;
    float zf = (g==0)?v1:(g==1)?v0:(g==2)?v3:v2;
    float zg = (g==0)?v2:(g==1)?v3:(g==2)?v0:v1;
    float zo = (g==0)?v3:(g==1)?v2:(g==2)?v1:v0;
    float cn = fsig(zf)*cs[r] + fsig(zi)*ftanhf(zg);
    cs[r] = cn;
    float hv = fsig(zo)*ftanhf(cn);
    unsigned hb16 = (unsigned)__builtin_bit_cast(unsigned short, (_Float16)hv);
    unsigned up   = (unsigned)__shfl_xor((int)hb16, 1, 64);
    if (g==0 && (c&1)==0)
      __hip_atomic_store((unsigned*)(dst + (mt*16 + q*4 + r)*1024 + wg*4 + c),
                         hb16 | (up<<16),
                         __ATOMIC_RELAXED, __HIP_MEMORY_SCOPE_AGENT);
  }
}

__global__ __launch_bounds__(128, 1) void lstm_persist(
    const _Float16* __restrict__ wrec, const _Float16* __restrict__ zx0,
    const float* __restrict__ b1g, _Float16* __restrict__ h0a,
    _Float16* __restrict__ h1a, unsigned int* __restrict__ flags)
{
  extern __shared__ _Float16 lds[];
  _Float16* w0  = lds;            // 16384 halves
  _Float16* w1  = lds + 16384;
  _Float16* w2  = lds + 32768;

  const int wg = blockIdx.x, tid = threadIdx.x;
  const int wv = tid>>6, l = tid&63, q = l>>4, c = l&15;
  const int g = (c>>2);           // gate of own column
  const int mt = wv;              // wave0 rows 0-15, wave1 rows 16-31
  const int row = mt*16 + c;      // A-frag row this lane loads
  const int grp = wg >> 3;        // 32 groups of 8

  unsigned int* gcnt = flags + grp*64;        // leaf lines, 256B apart
  unsigned int* root = flags + 2048;          // own line @8KiB
  unsigned int* go   = flags + 4096;          // PRIVATE go[wg] @16KiB + wg*256B

  { // stage this WG's weight slice: 98304 B = 6144 uint4
    const uint4* src = (const uint4*)(wrec + (size_t)wg*49152);
    uint4* dst = (uint4*)lds;
    for (int i=tid; i<6144; i+=128) dst[i] = src[i];
  }
  float c0[4] = {0,0,0,0}, c1[4] = {0,0,0,0};
  const float b1v = b1g[g*1024 + wg*4 + (c&3)];
  __syncthreads();

  // ---------- prologue: A(0): h0(0) = act(Zx0[0]) (h0(-1)=0) ----------
  {
    const _Float16* zsrc = zx0 + ((size_t)wg*32 + mt*16 + q*4)*16 + c;
    floatx4 a;
    a[0]=(float)zsrc[0]; a[1]=(float)zsrc[16]; a[2]=(float)zsrc[32]; a[3]=(float)zsrc[48];
    gates_store(a, c0, h0a, g, c, mt, q, wg);   // t = 0
  }

  for (int t=0; t<512; ++t){
    // prefetch zx0 for A(t+1) (register-resident across the barrier)
    int tn = (t<511) ? t+1 : 511;
    const _Float16* zsrc = zx0 + ((size_t)(tn*256 + wg)*32 + mt*16 + q*4)*16 + c;
    float pz0=(float)zsrc[0], pz1=(float)zsrc[16], pz2=(float)zsrc[32], pz3=(float)zsrc[48];

    __syncthreads();   // drains vmcnt: h0(t)/h1(t-1) stores visible at LLC

    // ---------- barrier: tree arrive + PARALLEL release ----------
    const unsigned tgt = (unsigned)(t+1);
    if (wv == 0){
      int amroot = 0;
      if (l == 0){
        unsigned o = __hip_atomic_fetch_add(gcnt, 1u, __ATOMIC_RELAXED,
                                            __HIP_MEMORY_SCOPE_AGENT);
        if (o == 8u*tgt - 1u){
          unsigned r = __hip_atomic_fetch_add(root, 1u, __ATOMIC_RELAXED,
                                              __HIP_MEMORY_SCOPE_AGENT);
          if (r == 32u*tgt - 1u) amroot = 1;
        }
      }
      amroot = __shfl(amroot, 0, 64);
      if (amroot){
        // wave-parallel broadcast: 64 lanes x 4 stores = 256 private go lines
        #pragma unroll
        for (int k2=0; k2<4; ++k2)
          __hip_atomic_store(go + (size_t)(l*4+k2)*64, tgt,
                             __ATOMIC_RELAXED, __HIP_MEMORY_SCOPE_AGENT);
      }
      if (l == 0){
        // tight poll on private line (1 writer, 1 poller — no congestion)
        while (__hip_atomic_load(go + (size_t)wg*64, __ATOMIC_RELAXED,
                                 __HIP_MEMORY_SCOPE_AGENT) < tgt)
          ;
      }
    }
    __syncthreads();
    // NO acquire fence: h0a[t]/h1a[t-1] lines are fresh by construction
    // (never cached by any XCD before this read; producers stored uncached
    // to LLC). zx0/weights are read-only; __syncthreads orders compiler+HW.

    // ---------- register-batched loads: all 64 fragments in flight --------
    const _Float16* h0c = h0a + (size_t)t*32768 + row*1024 + q*8;
    const _Float16* h1p = h1a + (size_t)(t-1)*32768 + row*1024 + q*8;
    half8 H1[32], H0[32];
    if (t > 0){
      #pragma unroll
      for (int s=0; s<32; ++s) H1[s] = AF(h1p, s);
    }
    #pragma unroll
    for (int s=0; s<32; ++s) H0[s] = AF(h0c, s);

    // ---------- merged compute: B(t) and A(t+1) ----------
    floatx4 aA0={0,0,0,0}, aA1={0,0,0,0};
    floatx4 aB0={b1v,b1v,b1v,b1v}, aB1={0,0,0,0};
    floatx4 aC0={0,0,0,0}, aC1={0,0,0,0};
    if (t > 0){
      #pragma unroll
      for (int s=0; s<16; ++s){
        aC0 = __builtin_amdgcn_mfma_f32_16x16x32_f16(H1[s],    BF(w2,s),    aC0,0,0,0);
        aC1 = __builtin_amdgcn_mfma_f32_16x16x32_f16(H1[16+s], BF(w2,16+s), aC1,0,0,0);
      }
    }
    #pragma unroll
    for (int s=0; s<16; ++s){
      aB0 = __builtin_amdgcn_mfma_f32_16x16x32_f16(H0[s],    BF(w1,s),    aB0,0,0,0);
      aB1 = __builtin_amdgcn_mfma_f32_16x16x32_f16(H0[16+s], BF(w1,16+s), aB1,0,0,0);
      aA0 = __builtin_amdgcn_mfma_f32_16x16x32_f16(H0[s],    BF(w0,s),    aA0,0,0,0);
      aA1 = __builtin_amdgcn_mfma_f32_16x16x32_f16(H0[16+s], BF(w0,16+s), aA1,0,0,0);
    }
    // B(t): h1(t)
    {
      floatx4 z1 = (aB0+aB1)+(aC0+aC1);
      gates_store(z1, c1, h1a + (size_t)t*32768, g, c, mt, q, wg);
    }
    // A(t+1): h0(t+1)
    if (t < 511){
      floatx4 z0 = aA0+aA1;
      z0[0]+=pz0; z0[1]+=pz1; z0[2]+=pz2; z0[3]+=pz3;
      gates_store(z0, c0, h0a + (size_t)(t+1)*32768, g, c, mt, q, wg);
    }
  }
}

// ---------------- Y = H1 @ Wd + bd -----------------------------------------
__global__ __launch_bounds__(256) void wd_gemm(const _Float16* __restrict__ h1a,
                                               const _Float16* __restrict__ wda,
                                               const float* __restrict__ bd,
                                               float* __restrict__ y){
  int mb = blockIdx.x;   // 512 blocks of 32 rows (rows = t*32+b)
  int nb = blockIdx.y;   // 4 blocks of 128 cols
  int tid = threadIdx.x, wv = tid>>6, l = tid&63, q = l>>4, c = l&15;
  int mt = wv & 1, nh = wv >> 1;
  floatx4 acc[4];
  #pragma unroll
  for (int gg=0; gg<4; ++gg) acc[gg] = (floatx4){0.f,0.f,0.f,0.f};
  const _Float16* arow = h1a + (size_t)(mb*32 + mt*16 + c)*1024;
  #pragma unroll 4
  for (int ks=0; ks<32; ++ks){
    int kc = ks*4 + q;
    half8 a = *(const half8*)(arow + kc*8);
    #pragma unroll
    for (int gg=0; gg<4; ++gg){
      int nt = nb*8 + nh*4 + gg;
      half8 b = *(const half8*)(wda + ((size_t)(nt*128 + kc)*16 + c)*8);
      acc[gg] = __builtin_amdgcn_mfma_f32_16x16x32_f16(a,b,acc[gg],0,0,0);
    }
  }
  #pragma unroll
  for (int gg=0; gg<4; ++gg){
    int o = nb*128 + nh*64 + gg*16 + c;
    float bdv = bd[o];
    #pragma unroll
    for (int r=0;r<4;++r){
      int row = mb*32 + mt*16 + q*4 + r;
      int tt = row >> 5, bb = row & 31;
      y[(size_t)bb*262144 + tt*512 + o] = acc[gg][r] + bdv;
    }
  }
}

// ---------------------------------------------------------------------------
extern "C" void kernel_launch(void* const* d_in, const int* in_sizes, int n_in,
                              void* d_out, int out_size, void* d_ws, size_t ws_size,
                              hipStream_t stream){
  const float* x   = (const float*)d_in[0];
  const float* Wx0 = (const float*)d_in[1];
  const float* Wh0 = (const float*)d_in[2];
  const float* b0  = (const float*)d_in[3];
  const float* Wx1 = (const float*)d_in[4];
  const float* Wh1 = (const float*)d_in[5];
  const float* b1  = (const float*)d_in[6];
  const float* Wd  = (const float*)d_in[7];
  const float* bd  = (const float*)d_in[8];
  float* y = (float*)d_out;
  char* ws = (char*)d_ws;

  _Float16* wrec = (_Float16*)(ws + WREC_OFF);
  _Float16* wx0a = (_Float16*)(ws + WX0_OFF);
  _Float16* wda  = (_Float16*)(ws + WD_OFF);
  _Float16* xh   = (_Float16*)(ws + XH_OFF);
  _Float16* zx0  = (_Float16*)(ws + ZX0_OFF);
  _Float16* h1a  = (_Float16*)(ws + H1_OFF);
  _Float16* h0a  = (_Float16*)(ws + H0_OFF);
  unsigned int* flags = (unsigned int*)(ws + FLAGS_OFF);

  hipMemsetAsync(flags, 0, 81920, stream);
  conv_wrec<<<dim3(6144), dim3(256), 0, stream>>>(Wh0, Wx1, Wh1, wrec);
  conv_wx0 <<<dim3(1024), dim3(256), 0, stream>>>(Wx0, wx0a);
  conv_wd  <<<dim3(256),  dim3(256), 0, stream>>>(Wd, wda);
  conv_x   <<<dim3(8192), dim3(256), 0, stream>>>(x, xh);
  zx0_gemm <<<dim3(512,64), dim3(64), 0, stream>>>(xh, wx0a, b0, zx0);
  hipFuncSetAttribute((const void*)lstm_persist,
                      hipFuncAttributeMaxDynamicSharedMemorySize, 98304);
  lstm_persist<<<dim3(256), dim3(128), 98304, stream>>>(wrec, zx0, b1, h0a, h1a, flags);
  wd_gemm  <<<dim3(512,4), dim3(256), 0, stream>>>(h1a, wda, bd, y);
}

// Round 9
// 4843.519 us; speedup vs baseline: 1.1831x; 1.0477x over previous
//
#include <hip/hip_runtime.h>

// ---------------------------------------------------------------------------
// SimpleLSTM: 2-layer LSTM (B=32,T=512,D=512,H=1024) + output proj (O=512).
//   conv kernels : fp32 -> f16, weights rearranged into MFMA B-frag order
//   zx0_gemm     : Zx0[t][wg][m][c] = x@Wx0 + b0  (parallel over all T)
//   lstm_persist : 256 persistent WGs (1/CU), recurrent weights in LDS
//   wd_gemm      : Y = H1 @ Wd + bd
// R4: tree barrier, 1 barrier/step (22.7 -> 14.5 ms).
// R5: uncached h-exchange stores, direct-from-global A-frags (14.5 -> 8.3).
// R6: poll de-congestion + merged B(t)/A(t+1) phase (8.3 -> 7.6).
// R7: NO FENCES. h1a t-indexed; fresh-line reads need no invalidate (7.6->6.6).
// R8: h0a t-indexed too; all h reads plain cached loads (6.6 -> 5.8).
// R9: flat zero-RMW barrier — REGRESSED; reverted.
// R10: register-batched h loads (64 frags in flight) (5.4 -> 4.8 persist).
// R11: in-loop Wx0 fusion — REGRESSED; reverted (zx0 precompute restored).
// R12: split-phase dual barrier — REGRESSED (+1 sync, +1 tree).
// R13: gated L2 prefetch during wait — REGRESSED (poll overhead > benefit).
// R14: direct 32-line wave-poll by ALL WGs — REGRESSED (8192 pollers
//     congested the leaf lines). Lesson: line congestion >> hop count.
// R15: parallel release + private go lines — NEUTRAL (release micro-
//     structure exonerated; root level + straggler asymmetry remain).
// R16: READER-DETECTOR BARRIER (no root level) + zx0 in wait shadow:
//     (a) WG0's wave0, during its idle wait, polls the 32 leaf lines
//         (32 pollers total — R14's congestion was 8192), ballots, then
//         broadcasts 256 PRIVATE go lines in parallel (R15 mechanism).
//         Leaf winners no longer RMW a root: the serialized 32-RMW root
//         chain and the root-winner straggler asymmetry are DELETED.
//     (b) zx0 prefetch issued AFTER the leaf arrive: its HBM latency
//         (~0.4us) leaves the pre-barrier vmcnt drain and completes
//         during the wait.
// ---------------------------------------------------------------------------

typedef _Float16 half8  __attribute__((ext_vector_type(8)));
typedef float    floatx4 __attribute__((ext_vector_type(4)));

// ws layout (bytes)
#define WREC_OFF   0UL            // [256 wg][3 mat][128 kc][16 c][8] f16 = 24 MiB
#define WX0_OFF    25165824UL     // [256 wg][64 kc][16 c][8] f16        = 4 MiB
#define WD_OFF     29360128UL     // [32 nt][128 kc][16 c][8] f16        = 1 MiB
#define XH_OFF     30408704UL     // [512 t][32 b][512 d] f16            = 16 MiB
#define ZX0_OFF    47185920UL     // [512 t][256 wg][32 m][16 c] f16     = 128 MiB
#define H1_OFF     181403648UL    // [512 t][32 m][1024 k] f16           = 32 MiB
#define H0_OFF     214958080UL    // [512 t][32 m][1024 k] f16           = 32 MiB
#define FLAGS_OFF  248512512UL    // 80 KiB: gcnt[32]@256B, go[256]@16K+256B

__device__ __forceinline__ float fsig(float x){ return 1.0f/(1.0f + __expf(-x)); }
__device__ __forceinline__ float ftanhf(float x){
  float e = __expf(2.0f*fabsf(x));
  float r = 1.0f - 2.0f/(e + 1.0f);
  return copysignf(r, x);
}

// ---------------- weight conversion ----------------------------------------
__global__ void conv_wrec(const float* __restrict__ Wh0,
                          const float* __restrict__ Wx1,
                          const float* __restrict__ Wh1,
                          _Float16* __restrict__ out){
  int idx = blockIdx.x*256 + threadIdx.x;          // ((wg*3+mat)*128+kc)*16+c
  if (idx >= 256*3*128*16) return;
  int c  = idx & 15;
  int t1 = idx >> 4;
  int kc = t1 & 127;
  int t2 = t1 >> 7;
  int mat = t2 % 3;
  int wg  = t2 / 3;
  const float* W = (mat==0) ? Wh0 : (mat==1) ? Wx1 : Wh1;
  int col = (c>>2)*1024 + wg*4 + (c&3);
  _Float16* o = out + (size_t)idx*8;
  #pragma unroll
  for (int j=0;j<8;++j) o[j] = (_Float16)W[(kc*8+j)*4096 + col];
}

__global__ void conv_wx0(const float* __restrict__ W, _Float16* __restrict__ out){
  int idx = blockIdx.x*256 + threadIdx.x;          // ((wg*64+kc)*16+c)
  if (idx >= 256*64*16) return;
  int c  = idx & 15;
  int kc = (idx >> 4) & 63;
  int wg = idx >> 10;
  int col = (c>>2)*1024 + wg*4 + (c&3);
  _Float16* o = out + (size_t)idx*8;
  #pragma unroll
  for (int j=0;j<8;++j) o[j] = (_Float16)W[(kc*8+j)*4096 + col];
}

__global__ void conv_wd(const float* __restrict__ W, _Float16* __restrict__ out){
  int idx = blockIdx.x*256 + threadIdx.x;          // ((nt*128+kc)*16+c)
  if (idx >= 32*128*16) return;
  int c  = idx & 15;
  int kc = (idx >> 4) & 127;
  int nt = idx >> 11;
  int col = nt*16 + c;
  _Float16* o = out + (size_t)idx*8;
  #pragma unroll
  for (int j=0;j<8;++j) o[j] = (_Float16)W[(kc*8+j)*512 + col];
}

// x[b][t][d] fp32 -> xh[t*32+b][d] f16  (time-major rows for zx0_gemm)
__global__ void conv_x(const float* __restrict__ x, _Float16* __restrict__ xh){
  int idx = blockIdx.x*256 + threadIdx.x;          // [bt][dq], dq = d/4
  if (idx >= 2097152) return;
  int dq = idx & 127;
  int bt = idx >> 7;          // t*32 + b
  int b  = bt & 31;
  int t  = bt >> 5;
  float4 v = ((const float4*)x)[(size_t)(b*512 + t)*128 + dq];
  _Float16* o = xh + (size_t)idx*4;
  o[0]=(_Float16)v.x; o[1]=(_Float16)v.y; o[2]=(_Float16)v.z; o[3]=(_Float16)v.w;
}

// ---------------- Zx0 = x @ Wx0 + b0 ---------------------------------------
__global__ __launch_bounds__(64) void zx0_gemm(const _Float16* __restrict__ xh,
                                               const _Float16* __restrict__ wx0a,
                                               const float* __restrict__ b0,
                                               _Float16* __restrict__ zx0){
  int t   = blockIdx.x;        // 512
  int wgg = blockIdx.y;        // 64 (covers 4 wg slices)
  int l = threadIdx.x, q = l>>4, c = l&15;
  floatx4 acc[2][4];
  #pragma unroll
  for (int g=0; g<4; ++g){
    int wg = wgg*4+g;
    float bv = b0[(c>>2)*1024 + wg*4 + (c&3)];
    acc[0][g] = (floatx4){bv,bv,bv,bv};
    acc[1][g] = (floatx4){bv,bv,bv,bv};
  }
  #pragma unroll 4
  for (int ks=0; ks<16; ++ks){
    int kc = ks*4 + q;
    half8 a0 = *(const half8*)(xh + (t*32      + c)*512 + kc*8);
    half8 a1 = *(const half8*)(xh + (t*32 + 16 + c)*512 + kc*8);
    #pragma unroll
    for (int g=0; g<4; ++g){
      int wg = wgg*4+g;
      half8 b = *(const half8*)(wx0a + ((size_t)(wg*64 + kc)*16 + c)*8);
      acc[0][g] = __builtin_amdgcn_mfma_f32_16x16x32_f16(a0,b,acc[0][g],0,0,0);
      acc[1][g] = __builtin_amdgcn_mfma_f32_16x16x32_f16(a1,b,acc[1][g],0,0,0);
    }
  }
  #pragma unroll
  for (int g=0; g<4; ++g){
    int wg = wgg*4+g;
    #pragma unroll
    for (int mt=0; mt<2; ++mt)
      #pragma unroll
      for (int r=0;r<4;++r){
        int m = mt*16 + q*4 + r;
        zx0[((size_t)(t*256 + wg)*32 + m)*16 + c] = (_Float16)acc[mt][g][r];
      }
  }
}

// ---------------- persistent recurrent kernel ------------------------------
// LDS: w0 (Wh0), w1 (Wx1), w2 (Wh1): [128 kc][16 c][8] each = 96 KiB total
#define AF(base, ks)  (*(const half8*)((base) + (ks)*32))
#define BF(w, ks)     (*(const half8*)((w) + (((ks)*4 + q)*16 + c)*8))

// gate exchange + cell update + packed agent-scope store of h (cols wg*4..+3)
__device__ __forceinline__ void gates_store(floatx4 acc, float* cs,
    _Float16* dst, int g, int c, int mt, int q, int wg){
  #pragma unroll
  for (int r=0;r<4;++r){
    float v0 = acc[r];
    float v1 = __shfl_xor(v0, 4, 64);
    float v2 = __shfl_xor(v0, 8, 64);
    float v3 = __shfl_xor(v1, 8, 64);
    float zi = (g==0)?v0:(g==1)?v1:(g==2)?v2:v3;
    float zf = (g==0)?v1:(g==1)?v0:(g==2)?v3:v2;
    float zg = (g==0)?v2:(g==1)?v3:(g==2)?v0:v1;
    float zo = (g==0)?v3:(g==1)?v2:(g==2)?v1:v0;
    float cn = fsig(zf)*cs[r] + fsig(zi)*ftanhf(zg);
    cs[r] = cn;
    float hv = fsig(zo)*ftanhf(cn);
    unsigned hb16 = (unsigned)__builtin_bit_cast(unsigned short, (_Float16)hv);
    unsigned up   = (unsigned)__shfl_xor((int)hb16, 1, 64);
    if (g==0 && (c&1)==0)
      __hip_atomic_store((unsigned*)(dst + (mt*16 + q*4 + r)*1024 + wg*4 + c),
                         hb16 | (up<<16),
                         __ATOMIC_RELAXED, __HIP_MEMORY_SCOPE_AGENT);
  }
}

__global__ __launch_bounds__(128, 1) void lstm_persist(
    const _Float16* __restrict__ wrec, const _Float16* __restrict__ zx0,
    const float* __restrict__ b1g, _Float16* __restrict__ h0a,
    _Float16* __restrict__ h1a, unsigned int* __restrict__ flags)
{
  extern __shared__ _Float16 lds[];
  _Float16* w0  = lds;            // 16384 halves
  _Float16* w1  = lds + 16384;
  _Float16* w2  = lds + 32768;

  const int wg = blockIdx.x, tid = threadIdx.x;
  const int wv = tid>>6, l = tid&63, q = l>>4, c = l&15;
  const int g = (c>>2);           // gate of own column
  const int mt = wv;              // wave0 rows 0-15, wave1 rows 16-31
  const int row = mt*16 + c;      // A-frag row this lane loads
  const int grp = wg >> 3;        // 32 groups of 8

  unsigned int* gcnt = flags + grp*64;        // leaf lines, 256B apart
  unsigned int* go   = flags + 4096;          // PRIVATE go[wg] @16KiB + wg*256B

  { // stage this WG's weight slice: 98304 B = 6144 uint4
    const uint4* src = (const uint4*)(wrec + (size_t)wg*49152);
    uint4* dst = (uint4*)lds;
    for (int i=tid; i<6144; i+=128) dst[i] = src[i];
  }
  float c0[4] = {0,0,0,0}, c1[4] = {0,0,0,0};
  const float b1v = b1g[g*1024 + wg*4 + (c&3)];
  __syncthreads();

  // ---------- prologue: A(0): h0(0) = act(Zx0[0]) (h0(-1)=0) ----------
  {
    const _Float16* zsrc = zx0 + ((size_t)wg*32 + mt*16 + q*4)*16 + c;
    floatx4 a;
    a[0]=(float)zsrc[0]; a[1]=(float)zsrc[16]; a[2]=(float)zsrc[32]; a[3]=(float)zsrc[48];
    gates_store(a, c0, h0a, g, c, mt, q, wg);   // t = 0
  }

  for (int t=0; t<512; ++t){
    __syncthreads();   // drains vmcnt: h0(t)/h1(t-1) stores visible at LLC

    // ---------- barrier arrive: one leaf RMW per WG (no root level) -------
    const unsigned tgt = (unsigned)(t+1);
    if (tid == 0)
      __hip_atomic_fetch_add(gcnt, 1u, __ATOMIC_RELAXED,
                             __HIP_MEMORY_SCOPE_AGENT);

    // ---------- zx0 prefetch for A(t+1): completes in the wait shadow ----
    int tn = (t<511) ? t+1 : 511;
    const _Float16* zsrc = zx0 + ((size_t)(tn*256 + wg)*32 + mt*16 + q*4)*16 + c;
    float pz0=(float)zsrc[0], pz1=(float)zsrc[16], pz2=(float)zsrc[32], pz3=(float)zsrc[48];

    // ---------- detect + release ----------
    if (wg == 0 && wv == 0){
      // WG0 wave0: reader-detector. 32 lanes poll 32 leaf lines (1 each),
      // then all 64 lanes broadcast 256 private go lines in parallel.
      const unsigned thr = 8u*tgt;
      const unsigned int* myleaf = flags + l*64;
      for (;;){
        unsigned v = 0xffffffffu;
        if (l < 32)
          v = __hip_atomic_load(myleaf, __ATOMIC_RELAXED,
                                __HIP_MEMORY_SCOPE_AGENT);
        if (__ballot(v >= thr) == 0xffffffffffffffffULL) break;
      }
      #pragma unroll
      for (int k2=0; k2<4; ++k2)
        __hip_atomic_store(go + (size_t)(l*4+k2)*64, tgt,
                           __ATOMIC_RELAXED, __HIP_MEMORY_SCOPE_AGENT);
    } else if (wg != 0 && tid == 0){
      // tight poll on private line (1 writer, 1 poller — no congestion)
      while (__hip_atomic_load(go + (size_t)wg*64, __ATOMIC_RELAXED,
                               __HIP_MEMORY_SCOPE_AGENT) < tgt)
        ;
    }
    __syncthreads();
    // NO acquire fence: h0a[t]/h1a[t-1] lines are fresh by construction
    // (never cached by any XCD before this read; producers stored uncached
    // to LLC). zx0/weights are read-only; __syncthreads orders compiler+HW.

    // ---------- register-batched loads: all 64 fragments in flight --------
    const _Float16* h0c = h0a + (size_t)t*32768 + row*1024 + q*8;
    const _Float16* h1p = h1a + (size_t)(t-1)*32768 + row*1024 + q*8;
    half8 H1[32], H0[32];
    if (t > 0){
      #pragma unroll
      for (int s=0; s<32; ++s) H1[s] = AF(h1p, s);
    }
    #pragma unroll
    for (int s=0; s<32; ++s) H0[s] = AF(h0c, s);

    // ---------- merged compute: B(t) and A(t+1) ----------
    floatx4 aA0={0,0,0,0}, aA1={0,0,0,0};
    floatx4 aB0={b1v,b1v,b1v,b1v}, aB1={0,0,0,0};
    floatx4 aC0={0,0,0,0}, aC1={0,0,0,0};
    if (t > 0){
      #pragma unroll
      for (int s=0; s<16; ++s){
        aC0 = __builtin_amdgcn_mfma_f32_16x16x32_f16(H1[s],    BF(w2,s),    aC0,0,0,0);
        aC1 = __builtin_amdgcn_mfma_f32_16x16x32_f16(H1[16+s], BF(w2,16+s), aC1,0,0,0);
      }
    }
    #pragma unroll
    for (int s=0; s<16; ++s){
      aB0 = __builtin_amdgcn_mfma_f32_16x16x32_f16(H0[s],    BF(w1,s),    aB0,0,0,0);
      aB1 = __builtin_amdgcn_mfma_f32_16x16x32_f16(H0[16+s], BF(w1,16+s), aB1,0,0,0);
      aA0 = __builtin_amdgcn_mfma_f32_16x16x32_f16(H0[s],    BF(w0,s),    aA0,0,0,0);
      aA1 = __builtin_amdgcn_mfma_f32_16x16x32_f16(H0[16+s], BF(w0,16+s), aA1,0,0,0);
    }
    // B(t): h1(t)
    {
      floatx4 z1 = (aB0+aB1)+(aC0+aC1);
      gates_store(z1, c1, h1a + (size_t)t*32768, g, c, mt, q, wg);
    }
    // A(t+1): h0(t+1)
    if (t < 511){
      floatx4 z0 = aA0+aA1;
      z0[0]+=pz0; z0[1]+=pz1; z0[2]+=pz2; z0[3]+=pz3;
      gates_store(z0, c0, h0a + (size_t)(t+1)*32768, g, c, mt, q, wg);
    }
  }
}

// ---------------- Y = H1 @ Wd + bd -----------------------------------------
__global__ __launch_bounds__(256) void wd_gemm(const _Float16* __restrict__ h1a,
                                               const _Float16* __restrict__ wda,
                                               const float* __restrict__ bd,
                                               float* __restrict__ y){
  int mb = blockIdx.x;   // 512 blocks of 32 rows (rows = t*32+b)
  int nb = blockIdx.y;   // 4 blocks of 128 cols
  int tid = threadIdx.x, wv = tid>>6, l = tid&63, q = l>>4, c = l&15;
  int mt = wv & 1, nh = wv >> 1;
  floatx4 acc[4];
  #pragma unroll
  for (int gg=0; gg<4; ++gg) acc[gg] = (floatx4){0.f,0.f,0.f,0.f};
  const _Float16* arow = h1a + (size_t)(mb*32 + mt*16 + c)*1024;
  #pragma unroll 4
  for (int ks=0; ks<32; ++ks){
    int kc = ks*4 + q;
    half8 a = *(const half8*)(arow + kc*8);
    #pragma unroll
    for (int gg=0; gg<4; ++gg){
      int nt = nb*8 + nh*4 + gg;
      half8 b = *(const half8*)(wda + ((size_t)(nt*128 + kc)*16 + c)*8);
      acc[gg] = __builtin_amdgcn_mfma_f32_16x16x32_f16(a,b,acc[gg],0,0,0);
    }
  }
  #pragma unroll
  for (int gg=0; gg<4; ++gg){
    int o = nb*128 + nh*64 + gg*16 + c;
    float bdv = bd[o];
    #pragma unroll
    for (int r=0;r<4;++r){
      int row = mb*32 + mt*16 + q*4 + r;
      int tt = row >> 5, bb = row & 31;
      y[(size_t)bb*262144 + tt*512 + o] = acc[gg][r] + bdv;
    }
  }
}

// ---------------------------------------------------------------------------
extern "C" void kernel_launch(void* const* d_in, const int* in_sizes, int n_in,
                              void* d_out, int out_size, void* d_ws, size_t ws_size,
                              hipStream_t stream){
  const float* x   = (const float*)d_in[0];
  const float* Wx0 = (const float*)d_in[1];
  const float* Wh0 = (const float*)d_in[2];
  const float* b0  = (const float*)d_in[3];
  const float* Wx1 = (const float*)d_in[4];
  const float* Wh1 = (const float*)d_in[5];
  const float* b1  = (const float*)d_in[6];
  const float* Wd  = (const float*)d_in[7];
  const float* bd  = (const float*)d_in[8];
  float* y = (float*)d_out;
  char* ws = (char*)d_ws;

  _Float16* wrec = (_Float16*)(ws + WREC_OFF);
  _Float16* wx0a = (_Float16*)(ws + WX0_OFF);
  _Float16* wda  = (_Float16*)(ws + WD_OFF);
  _Float16* xh   = (_Float16*)(ws + XH_OFF);
  _Float16* zx0  = (_Float16*)(ws + ZX0_OFF);
  _Float16* h1a  = (_Float16*)(ws + H1_OFF);
  _Float16* h0a  = (_Float16*)(ws + H0_OFF);
  unsigned int* flags = (unsigned int*)(ws + FLAGS_OFF);

  hipMemsetAsync(flags, 0, 81920, stream);
  conv_wrec<<<dim3(6144), dim3(256), 0, stream>>>(Wh0, Wx1, Wh1, wrec);
  conv_wx0 <<<dim3(1024), dim3(256), 0, stream>>>(Wx0, wx0a);
  conv_wd  <<<dim3(256),  dim3(256), 0, stream>>>(Wd, wda);
  conv_x   <<<dim3(8192), dim3(256), 0, stream>>>(x, xh);
  zx0_gemm <<<dim3(512,64), dim3(64), 0, stream>>>(xh, wx0a, b0, zx0);
  hipFuncSetAttribute((const void*)lstm_persist,
                      hipFuncAttributeMaxDynamicSharedMemorySize, 98304);
  lstm_persist<<<dim3(256), dim3(128), 98304, stream>>>(wrec, zx0, b1, h0a, h1a, flags);
  wd_gemm  <<<dim3(512,4), dim3(256), 0, stream>>>(h1a, wda, bd, y);
}